// Round 9
// baseline (321.240 us; speedup 1.0000x reference)
//
#include <hip/hip_runtime.h>
#include <hip/hip_bf16.h>
#include <hip/hip_fp8.h>

#define NN 50000
#define NE 800000
#define DIN 128
#define HC 256
#define NHEAD 4
#define CDIM 64
#define NGRAPH 512
#define NCLS 10
#define NEG_SLOPE 0.2f
#define NB 196   // ceil(NN/256)
#define NT1 3125 // NN/16 M-tiles

typedef __hip_bfloat16 bf16;
typedef __attribute__((ext_vector_type(8))) short short8;
typedef __attribute__((ext_vector_type(4))) float f32x4;
typedef __attribute__((ext_vector_type(2))) float f32x2;

__device__ __forceinline__ float bf2f(unsigned short u) {
  union { unsigned int i; float f; } x;
  x.i = ((unsigned int)u) << 16;
  return x.f;
}
__device__ __forceinline__ unsigned short f2bf(float f) {
  bf16 v = __float2bfloat16(f);
  union { bf16 b; unsigned short s; } x;
  x.b = v;
  return x.s;
}
// fp8 e4m3 (OCP) encode/decode via HIP type
__device__ __forceinline__ unsigned char f2f8(float f) {
  __hip_fp8_e4m3 q(f);
  return (unsigned char)q.__x;
}
__device__ __forceinline__ float lrelu(float x) { return x >= 0.f ? x : NEG_SLOPE * x; }
// NaN-propagating relu (fmaxf would silently clamp NaN to 0)
__device__ __forceinline__ float relu(float x) { return x < 0.f ? 0.f : x; }

// ---------------- zero scratch accumulators ----------------
__global__ void zero_kernel(int* __restrict__ p, int n) {
  int i = blockIdx.x * 256 + threadIdx.x;
  if (i < n) p[i] = 0;
}

// ---------------- repack W1,W2 into MFMA B-frag bf16 order + sentinel init ----------
// Sentinel: pad edges point to node NN; als[NN]=-1e30 -> w==0; payload rows NN zeroed.
__global__ void repack_kernel(const float* __restrict__ W1, const float* __restrict__ W2,
                              unsigned short* __restrict__ W1p, unsigned short* __restrict__ W2p,
                              float* __restrict__ als1, float* __restrict__ als2v,
                              unsigned char* __restrict__ h1f8, unsigned short* __restrict__ h2,
                              unsigned char* __restrict__ h2f8) {
  if (blockIdx.x == 0) {
    int t = threadIdx.x;
    if (t < NHEAD) als1[NN * NHEAD + t] = -1e30f;
    if (t == NHEAD) als2v[NN] = -1e30f;
    if (t < 64) ((unsigned int*)(h1f8 + (size_t)NN * HC))[t] = 0u;
    if (t < 32) ((unsigned int*)(h2 + (size_t)NN * CDIM))[t] = 0u;
    if (t < 16) ((unsigned int*)(h2f8 + (size_t)NN * CDIM))[t] = 0u;
  }
  int i = blockIdx.x * 256 + threadIdx.x;
  if (i < 16 * 4 * 64 * 8) {  // W1: [128,256] -> ng(16) kk(4) lane(64) j(8)
    int j = i & 7, lane = (i >> 3) & 63, kk = (i >> 9) & 3, ng = i >> 11;
    int n = ng * 16 + (lane & 15);
    int k = kk * 32 + (lane >> 4) * 8 + j;
    W1p[i] = f2bf(W1[k * HC + n]);
  }
  int i2 = i - 16 * 4 * 64 * 8;
  if (i2 >= 0 && i2 < 4 * 8 * 64 * 8) {  // W2: [256,64] -> ng(4) kk(8) lane(64) j(8)
    int j = i2 & 7, lane = (i2 >> 3) & 63, kk = (i2 >> 9) & 7, ng = i2 >> 12;
    int n = ng * 16 + (lane & 15);
    int k = kk * 32 + (lane >> 4) * 8 + j;
    W2p[i2] = f2bf(W2[k * CDIM + n]);
  }
}

// ---------------- GEMM1 + fused als1/ald1 + fused fp8 shadow write -------------------
__global__ __launch_bounds__(256) void gemm1_kernel(const float* __restrict__ x,
                                                    const unsigned short* __restrict__ W1p,
                                                    const float* __restrict__ a_src,
                                                    const float* __restrict__ a_dst,
                                                    unsigned short* __restrict__ h1,
                                                    unsigned char* __restrict__ h1f8,
                                                    float* __restrict__ als,
                                                    float* __restrict__ ald) {
  __shared__ float sh_as[HC], sh_ad[HC];
  {
    int t = threadIdx.x;
    sh_as[t] = a_src[t];
    sh_ad[t] = a_dst[t];
  }
  __syncthreads();
  int wave = threadIdx.x >> 6, lane = threadIdx.x & 63;
  int tile = blockIdx.x * 4 + wave;
  if (tile >= NT1) return;
  int r0 = tile * 16, m = lane & 15, quad = lane >> 4;
  int row = r0 + m;
  short8 a[4];
#pragma unroll
  for (int kk = 0; kk < 4; kk++) {
    int kb = kk * 32 + quad * 8;
    float4 f0 = *(const float4*)(x + row * DIN + kb);
    float4 f1 = *(const float4*)(x + row * DIN + kb + 4);
    alignas(16) unsigned short tmp[8];
    tmp[0] = f2bf(f0.x); tmp[1] = f2bf(f0.y); tmp[2] = f2bf(f0.z); tmp[3] = f2bf(f0.w);
    tmp[4] = f2bf(f1.x); tmp[5] = f2bf(f1.y); tmp[6] = f2bf(f1.z); tmp[7] = f2bf(f1.w);
    a[kk] = *(const short8*)tmp;
  }
#pragma unroll
  for (int hg = 0; hg < 4; hg++) {
    float ps[4] = {0.f, 0.f, 0.f, 0.f};
    float pd[4] = {0.f, 0.f, 0.f, 0.f};
#pragma unroll
    for (int sub = 0; sub < 4; sub++) {
      int ng = hg * 4 + sub;
      f32x4 acc = {0.f, 0.f, 0.f, 0.f};
#pragma unroll
      for (int kk = 0; kk < 4; kk++) {
        short8 b = *(const short8*)(W1p + ((ng * 4 + kk) * 64 + lane) * 8);
        acc = __builtin_amdgcn_mfma_f32_16x16x32_bf16(a[kk], b, acc, 0, 0, 0);
      }
      int col = ng * 16 + m;
      float asv = sh_as[col], adv = sh_ad[col];
#pragma unroll
      for (int r = 0; r < 4; r++) {
        int rr = r0 + quad * 4 + r;
        h1[rr * HC + col] = f2bf(acc[r]);
        h1f8[rr * HC + col] = f2f8(acc[r]);
        ps[r] += acc[r] * asv;
        pd[r] += acc[r] * adv;
      }
    }
#pragma unroll
    for (int o = 1; o < 16; o <<= 1) {
#pragma unroll
      for (int r = 0; r < 4; r++) {
        ps[r] += __shfl_xor(ps[r], o, 64);
        pd[r] += __shfl_xor(pd[r], o, 64);
      }
    }
    if (m == 0) {
#pragma unroll
      for (int r = 0; r < 4; r++) {
        int rr = r0 + quad * 4 + r;
        als[rr * NHEAD + hg] = ps[r];
        ald[rr * NHEAD + hg] = pd[r];
      }
    }
  }
}

// ---------------- edge histogram (deg by dst, 8-way sharded by e&7) ----------------
__global__ void hist_kernel(const int* __restrict__ ei, int* __restrict__ deg8) {
  int i = blockIdx.x * 256 + threadIdx.x;
  if (i < NE) atomicAdd(&deg8[(i & 7) * NN + ei[NE + i]], 1);
}

// ---------------- exclusive scan of 8-PADDED deg -> off, sharded cursors -------------
__global__ void scan_a(const int* __restrict__ deg8, int* __restrict__ bsum,
                       int* __restrict__ degsum) {
  __shared__ int sm[256];
  int t = threadIdx.x, i = blockIdx.x * 256 + t;
  int d = 0;
  if (i < NN) {
#pragma unroll
    for (int j = 0; j < 8; j++) d += deg8[j * NN + i];
  }
  int dp = (d + 7) & ~7;
  if (i < NN) degsum[i] = dp;
  sm[t] = dp;
  __syncthreads();
  for (int s = 128; s > 0; s >>= 1) {
    if (t < s) sm[t] += sm[t + s];
    __syncthreads();
  }
  if (t == 0) bsum[blockIdx.x] = sm[0];
}
// scan_c also performs scan_b's job: every block redundantly scans the 196
// block-sums in LDS (cheap) -- saves a kernel launch + dependency bubble.
__global__ void scan_c(const int* __restrict__ degsum, const int* __restrict__ deg8,
                       const int* __restrict__ bsum,
                       int* __restrict__ off, int* __restrict__ cursor8,
                       int* __restrict__ esrc) {
  __shared__ int sm[256];
  __shared__ int pre[256];
  int t = threadIdx.x, i = blockIdx.x * 256 + t;
  int own = (t < NB) ? bsum[t] : 0;
  sm[t] = own;
  pre[t] = own;
  __syncthreads();
  for (int s = 1; s < 256; s <<= 1) {
    int v = (t >= s) ? sm[t - s] : 0;
    __syncthreads();
    sm[t] += v;
    __syncthreads();
  }
  int bbase = sm[blockIdx.x] - pre[blockIdx.x];  // exclusive prefix of block sums
  __syncthreads();
  int dp = (i < NN) ? degsum[i] : 0;
  sm[t] = dp;
  __syncthreads();
  for (int s = 1; s < 256; s <<= 1) {
    int v = (t >= s) ? sm[t - s] : 0;
    __syncthreads();
    sm[t] += v;
    __syncthreads();
  }
  int excl = bbase + sm[t] - dp;
  if (i < NN) {
    off[i] = excl;
    int base = excl;
#pragma unroll
    for (int j = 0; j < 8; j++) {
      cursor8[j * NN + i] = base;
      base += deg8[j * NN + i];
    }
    // fill pad slots (at most 7) with the sentinel src (weight == 0, zero payload)
    for (int q = base; q < excl + dp; q++) esrc[q] = NN;
    if (i == NN - 1) off[NN] = excl + dp;
  }
}

// ---------------- XCD-affine scatter: block (chunk c, xcd x) scatters only ----------
// Separate lean kernel (VGPR ~28): full occupancy hides atomic/scatter latency.
// r8's fusion with gemm1 halved its occupancy (VGPR 64 envelope) and regressed.
__global__ void scatter_kernel(const int* __restrict__ ei, int* __restrict__ cursor8,
                               int* __restrict__ esrc) {
  int xcd = blockIdx.x & 7;
  int chunk = blockIdx.x >> 3;
  int lo = chunk * (NE / 256);
  int hi = lo + (NE / 256);
  for (int e = lo + threadIdx.x; e < hi; e += 256) {
    int d = ei[NE + e];
    if (d / (NN / 8) == xcd) {
      int s = ei[e];
      int p = atomicAdd(&cursor8[(e & 7) * NN + d], 1);
      esrc[p] = s;
    }
  }
}

// ---------------- GAT layer1 aggregation: wave/node, fp8 packed decode ---------------
// 2 edge-groups x 32 lanes x 8 fp8 channels, 8 gathers in flight, sentinel-padded
// CSR (no tail clamps), 16-slot main chunks + optional single 8-slot half-chunk.
__global__ __launch_bounds__(256) void agg1_kernel(const unsigned short* __restrict__ h1,
                                                   const unsigned char* __restrict__ h1f8,
                                                   const float* __restrict__ als,
                                                   const float* __restrict__ ald,
                                                   const int* __restrict__ off,
                                                   const int* __restrict__ esrc,
                                                   const float* __restrict__ b1,
                                                   unsigned short* __restrict__ out1) {
  int node = blockIdx.x * 4 + (threadIdx.x >> 6);
  int lane = threadIdx.x & 63;
  int eg = lane >> 5;
  int c0 = (lane & 31) * 8;
  int hh = c0 >> 6;
  int beg = off[node], end = off[node + 1];
  float aldh = ald[node * NHEAD + hh];
  float a[8] = {0.f, 0.f, 0.f, 0.f, 0.f, 0.f, 0.f, 0.f};
  float zz = 0.f;
  int k = beg;
  for (; k + 16 <= end; k += 16) {
    int s[8];
    float w[8];
    uint2 u[8];
#pragma unroll
    for (int j = 0; j < 8; j++) s[j] = esrc[k + 2 * j + eg];
#pragma unroll
    for (int j = 0; j < 8; j++) {
      w[j] = __expf(lrelu(als[s[j] * NHEAD + hh] + aldh));
      u[j] = *(const uint2*)(h1f8 + s[j] * HC + c0);
    }
#pragma unroll
    for (int j = 0; j < 8; j++) {
      f32x2 p0 = __builtin_amdgcn_cvt_pk_f32_fp8(u[j].x, false);
      f32x2 p1 = __builtin_amdgcn_cvt_pk_f32_fp8(u[j].x, true);
      f32x2 p2 = __builtin_amdgcn_cvt_pk_f32_fp8(u[j].y, false);
      f32x2 p3 = __builtin_amdgcn_cvt_pk_f32_fp8(u[j].y, true);
      a[0] += w[j] * p0.x; a[1] += w[j] * p0.y;
      a[2] += w[j] * p1.x; a[3] += w[j] * p1.y;
      a[4] += w[j] * p2.x; a[5] += w[j] * p2.y;
      a[6] += w[j] * p3.x; a[7] += w[j] * p3.y;
      zz += w[j];
    }
  }
  if (k < end) {  // exactly one 8-slot half-chunk
    int s[4];
    float w[4];
    uint2 u[4];
#pragma unroll
    for (int j = 0; j < 4; j++) s[j] = esrc[k + 2 * j + eg];
#pragma unroll
    for (int j = 0; j < 4; j++) {
      w[j] = __expf(lrelu(als[s[j] * NHEAD + hh] + aldh));
      u[j] = *(const uint2*)(h1f8 + s[j] * HC + c0);
    }
#pragma unroll
    for (int j = 0; j < 4; j++) {
      f32x2 p0 = __builtin_amdgcn_cvt_pk_f32_fp8(u[j].x, false);
      f32x2 p1 = __builtin_amdgcn_cvt_pk_f32_fp8(u[j].x, true);
      f32x2 p2 = __builtin_amdgcn_cvt_pk_f32_fp8(u[j].y, false);
      f32x2 p3 = __builtin_amdgcn_cvt_pk_f32_fp8(u[j].y, true);
      a[0] += w[j] * p0.x; a[1] += w[j] * p0.y;
      a[2] += w[j] * p1.x; a[3] += w[j] * p1.y;
      a[4] += w[j] * p2.x; a[5] += w[j] * p2.y;
      a[6] += w[j] * p3.x; a[7] += w[j] * p3.y;
      zz += w[j];
    }
  }
  // combine the two edge-groups (lanes L and L^32 cover the same channels)
#pragma unroll
  for (int j = 0; j < 8; j++) a[j] += __shfl_xor(a[j], 32, 64);
  zz += __shfl_xor(zz, 32, 64);
  if (eg == 0) {
    // self-loop from bf16 original
    float sw = __expf(lrelu(als[node * NHEAD + hh] + aldh));
    ushort4 vs0 = *(const ushort4*)(h1 + node * HC + c0);
    ushort4 vs1 = *(const ushort4*)(h1 + node * HC + c0 + 4);
    a[0] += sw * bf2f(vs0.x); a[1] += sw * bf2f(vs0.y);
    a[2] += sw * bf2f(vs0.z); a[3] += sw * bf2f(vs0.w);
    a[4] += sw * bf2f(vs1.x); a[5] += sw * bf2f(vs1.y);
    a[6] += sw * bf2f(vs1.z); a[7] += sw * bf2f(vs1.w);
    zz += sw;
    float inv = 1.f / zz;
    float4 bb0 = *(const float4*)(b1 + c0);
    float4 bb1 = *(const float4*)(b1 + c0 + 4);
    ushort4 o0, o1;
    o0.x = f2bf(a[0] * inv + bb0.x); o0.y = f2bf(a[1] * inv + bb0.y);
    o0.z = f2bf(a[2] * inv + bb0.z); o0.w = f2bf(a[3] * inv + bb0.w);
    o1.x = f2bf(a[4] * inv + bb1.x); o1.y = f2bf(a[5] * inv + bb1.y);
    o1.z = f2bf(a[6] * inv + bb1.z); o1.w = f2bf(a[7] * inv + bb1.w);
    *(ushort4*)(out1 + node * HC + c0) = o0;
    *(ushort4*)(out1 + node * HC + c0 + 4) = o1;
  }
}

// ---------------- BN stats over out1 ----------------
__global__ __launch_bounds__(256) void bnstats_kernel(const unsigned short* __restrict__ out1,
                                                      float* __restrict__ bnsum,
                                                      float* __restrict__ bnsumsq) {
  int t = threadIdx.x;
  float s = 0.f, s2 = 0.f;
  for (int r = blockIdx.x; r < NN; r += gridDim.x) {
    float v = bf2f(out1[r * HC + t]);
    s += v;
    s2 += v * v;
  }
  atomicAdd(&bnsum[t], s);
  atomicAdd(&bnsumsq[t], s2);
}

// ---------------- GEMM2 + fused als2/ald2 + fp8 shadow: h2 = relu(bn(out1)) @ W2 -----
__global__ __launch_bounds__(256) void gemm2_kernel(const unsigned short* __restrict__ out1,
                                                    const unsigned short* __restrict__ W2p,
                                                    const float* __restrict__ bnsum,
                                                    const float* __restrict__ bnsumsq,
                                                    const float* __restrict__ gamma,
                                                    const float* __restrict__ beta,
                                                    const float* __restrict__ a_src2,
                                                    const float* __restrict__ a_dst2,
                                                    unsigned short* __restrict__ h2,
                                                    unsigned char* __restrict__ h2f8,
                                                    float* __restrict__ als2,
                                                    float* __restrict__ ald2) {
  __shared__ float scale_s[HC], shift_s[HC];
  __shared__ float sh_as[CDIM], sh_ad[CDIM];
  {
    int t = threadIdx.x;
    float mu = bnsum[t] / (float)NN;
    float var = bnsumsq[t] / (float)NN - mu * mu;
    float sc = gamma[t] * rsqrtf(var + 1e-5f);
    scale_s[t] = sc;
    shift_s[t] = beta[t] - mu * sc;
    if (t < CDIM) {
      sh_as[t] = a_src2[t];
      sh_ad[t] = a_dst2[t];
    }
  }
  __syncthreads();
  int wave = threadIdx.x >> 6, lane = threadIdx.x & 63;
  int tile = blockIdx.x * 4 + wave;
  if (tile >= NT1) return;
  int r0 = tile * 16, m = lane & 15, quad = lane >> 4;
  int row = r0 + m;
  short8 a[8];
#pragma unroll
  for (int kk = 0; kk < 8; kk++) {
    int kb = kk * 32 + quad * 8;
    short8 raw = *(const short8*)(out1 + row * HC + kb);
    alignas(16) unsigned short tmp[8];
#pragma unroll
    for (int j = 0; j < 8; j++) {
      tmp[j] = f2bf(relu(bf2f((unsigned short)raw[j]) * scale_s[kb + j] + shift_s[kb + j]));
    }
    a[kk] = *(const short8*)tmp;
  }
  float ps[4] = {0.f, 0.f, 0.f, 0.f};
  float pd[4] = {0.f, 0.f, 0.f, 0.f};
#pragma unroll
  for (int ng = 0; ng < 4; ng++) {
    f32x4 acc = {0.f, 0.f, 0.f, 0.f};
#pragma unroll
    for (int kk = 0; kk < 8; kk++) {
      short8 b = *(const short8*)(W2p + ((ng * 8 + kk) * 64 + lane) * 8);
      acc = __builtin_amdgcn_mfma_f32_16x16x32_bf16(a[kk], b, acc, 0, 0, 0);
    }
    int col = ng * 16 + m;
    float asv = sh_as[col], adv = sh_ad[col];
#pragma unroll
    for (int r = 0; r < 4; r++) {
      int rr = r0 + quad * 4 + r;
      h2[rr * CDIM + col] = f2bf(acc[r]);
      h2f8[rr * CDIM + col] = f2f8(acc[r]);
      ps[r] += acc[r] * asv;
      pd[r] += acc[r] * adv;
    }
  }
#pragma unroll
  for (int o = 1; o < 16; o <<= 1) {
#pragma unroll
    for (int r = 0; r < 4; r++) {
      ps[r] += __shfl_xor(ps[r], o, 64);
      pd[r] += __shfl_xor(pd[r], o, 64);
    }
  }
  if (m == 0) {
#pragma unroll
    for (int r = 0; r < 4; r++) {
      int rr = r0 + quad * 4 + r;
      als2[rr] = ps[r];
      ald2[rr] = pd[r];
    }
  }
}

// ---------------- GAT layer2 agg + ReLU + pooling ----------------
// 4 edge-groups x 16 lanes x 4 fp8 channels (uint gathers into the 3.2MB L2-resident
// h2f8 table; bf16 self-loop keeps precision). Sentinel-padded CSR, 16-slot main
// chunks + optional 8-slot half-chunk. Pooled atomics block-combined in LDS.
__global__ __launch_bounds__(256) void agg2_kernel(const unsigned short* __restrict__ h2,
                                                   const unsigned char* __restrict__ h2f8,
                                                   const float* __restrict__ als2,
                                                   const float* __restrict__ ald2,
                                                   const int* __restrict__ off,
                                                   const int* __restrict__ esrc,
                                                   const float* __restrict__ b2,
                                                   const int* __restrict__ batch,
                                                   float* __restrict__ pooled) {
  __shared__ float svv[4][CDIM];
  __shared__ int sg[4];
  int wave = threadIdx.x >> 6;
  int node = blockIdx.x * 4 + wave;
  int lane = threadIdx.x & 63;
  int eg = lane >> 4;          // 4 edge groups
  int cp = (lane & 15) * 4;    // 4 channels per lane
  int beg = off[node], end = off[node + 1];
  float aldn = ald2[node];
  float a0 = 0.f, a1 = 0.f, a2 = 0.f, a3 = 0.f, zz = 0.f;
  int k = beg;
  for (; k + 16 <= end; k += 16) {
    int s[4];
    float w[4];
    unsigned int u[4];
#pragma unroll
    for (int j = 0; j < 4; j++) s[j] = esrc[k + 4 * j + eg];
#pragma unroll
    for (int j = 0; j < 4; j++) {
      w[j] = __expf(lrelu(als2[s[j]] + aldn));
      u[j] = *(const unsigned int*)(h2f8 + s[j] * CDIM + cp);
    }
#pragma unroll
    for (int j = 0; j < 4; j++) {
      f32x2 p0 = __builtin_amdgcn_cvt_pk_f32_fp8(u[j], false);
      f32x2 p1 = __builtin_amdgcn_cvt_pk_f32_fp8(u[j], true);
      a0 += w[j] * p0.x;
      a1 += w[j] * p0.y;
      a2 += w[j] * p1.x;
      a3 += w[j] * p1.y;
      zz += w[j];
    }
  }
  if (k < end) {  // exactly one 8-slot half-chunk
    int s[2];
    float w[2];
    unsigned int u[2];
#pragma unroll
    for (int j = 0; j < 2; j++) s[j] = esrc[k + 4 * j + eg];
#pragma unroll
    for (int j = 0; j < 2; j++) {
      w[j] = __expf(lrelu(als2[s[j]] + aldn));
      u[j] = *(const unsigned int*)(h2f8 + s[j] * CDIM + cp);
    }
#pragma unroll
    for (int j = 0; j < 2; j++) {
      f32x2 p0 = __builtin_amdgcn_cvt_pk_f32_fp8(u[j], false);
      f32x2 p1 = __builtin_amdgcn_cvt_pk_f32_fp8(u[j], true);
      a0 += w[j] * p0.x;
      a1 += w[j] * p0.y;
      a2 += w[j] * p1.x;
      a3 += w[j] * p1.y;
      zz += w[j];
    }
  }
  // combine the four edge-groups (lanes sharing (lane&15) cover same channels)
  a0 += __shfl_xor(a0, 16, 64); a0 += __shfl_xor(a0, 32, 64);
  a1 += __shfl_xor(a1, 16, 64); a1 += __shfl_xor(a1, 32, 64);
  a2 += __shfl_xor(a2, 16, 64); a2 += __shfl_xor(a2, 32, 64);
  a3 += __shfl_xor(a3, 16, 64); a3 += __shfl_xor(a3, 32, 64);
  zz += __shfl_xor(zz, 16, 64); zz += __shfl_xor(zz, 32, 64);
  if (eg == 0) {
    float sw = __expf(lrelu(als2[node] + aldn));
    ushort4 vs = *(const ushort4*)(h2 + node * CDIM + cp);
    a0 += sw * bf2f(vs.x);
    a1 += sw * bf2f(vs.y);
    a2 += sw * bf2f(vs.z);
    a3 += sw * bf2f(vs.w);
    zz += sw;
    float inv = 1.f / zz;
    float4 bb = *(const float4*)(b2 + cp);
    svv[wave][cp + 0] = relu(a0 * inv + bb.x);
    svv[wave][cp + 1] = relu(a1 * inv + bb.y);
    svv[wave][cp + 2] = relu(a2 * inv + bb.z);
    svv[wave][cp + 3] = relu(a3 * inv + bb.w);
    if (lane == 0) sg[wave] = batch[node];
  }
  __syncthreads();
  int t = threadIdx.x;
  if (t < CDIM) {
    int g0 = sg[0], g1 = sg[1], g2 = sg[2], g3 = sg[3];
#pragma unroll
    for (int w = 0; w < 4; w++) {
      int gs[4] = {g0, g1, g2, g3};
      int gw = gs[w];
      bool first = true;
#pragma unroll
      for (int w2 = 0; w2 < 4; w2++)
        if (w2 < w && gs[w2] == gw) first = false;
      if (first) {
        float acc = svv[w][t];
#pragma unroll
        for (int w2 = 0; w2 < 4; w2++)
          if (w2 > w && gs[w2] == gw) acc += svv[w2][t];
        atomicAdd(&pooled[gw * CDIM + t], acc);
      }
    }
  }
}

// ---------------- pooled mean + classifier (f32 output); counts via binary search ----
__global__ void cls_kernel(const float* __restrict__ pooled, const int* __restrict__ batch,
                           const float* __restrict__ cW1, const float* __restrict__ cb1,
                           const float* __restrict__ cW2, const float* __restrict__ cb2,
                           float* __restrict__ out) {
  __shared__ float p[64];
  __shared__ float z[32];
  int g = blockIdx.x, t = threadIdx.x;
  int lo = 0, hi = NN;
  while (lo < hi) { int mid = (lo + hi) >> 1; if (batch[mid] < g) lo = mid + 1; else hi = mid; }
  int start = lo;
  lo = 0; hi = NN;
  while (lo < hi) { int mid = (lo + hi) >> 1; if (batch[mid] <= g) lo = mid + 1; else hi = mid; }
  int c = lo - start;
  float cnt = (float)(c > 0 ? c : 1);
  p[t] = pooled[g * CDIM + t] / cnt;
  __syncthreads();
  if (t < 32) {
    float a = cb1[t];
    for (int k = 0; k < 64; k++) a += p[k] * cW1[k * 32 + t];
    z[t] = relu(a);
  }
  __syncthreads();
  if (t < NCLS) {
    float a = cb2[t];
    for (int k = 0; k < 32; k++) a += z[k] * cW2[k * NCLS + t];
    out[g * NCLS + t] = a;
  }
}

extern "C" void kernel_launch(void* const* d_in, const int* in_sizes, int n_in,
                              void* d_out, int out_size, void* d_ws, size_t ws_size,
                              hipStream_t stream) {
  const float* x = (const float*)d_in[0];
  const int* edge_index = (const int*)d_in[1];
  const int* batch = (const int*)d_in[2];
  const float* W1 = (const float*)d_in[3];
  const float* a_src1 = (const float*)d_in[4];
  const float* a_dst1 = (const float*)d_in[5];
  const float* b1 = (const float*)d_in[6];
  const float* gamma = (const float*)d_in[7];
  const float* beta = (const float*)d_in[8];
  const float* W2 = (const float*)d_in[9];
  const float* a_src2 = (const float*)d_in[10];
  const float* a_dst2 = (const float*)d_in[11];
  const float* b2 = (const float*)d_in[12];
  const float* cW1 = (const float*)d_in[13];
  const float* cb1 = (const float*)d_in[14];
  const float* cW2 = (const float*)d_in[15];
  const float* cb2 = (const float*)d_in[16];

  // ---- workspace layout ----
  // zero region (contiguous, zeroed every call): deg8 | bnsum | bnsumsq | pooled
  int* deg8 = (int*)d_ws;
  float* bnsum = (float*)(deg8 + 8 * NN);
  float* bnsumsq = bnsum + HC;
  float* pooled = bnsumsq + HC;
  const int ZWORDS = 8 * NN + HC + HC + NGRAPH * CDIM;
  char* p = (char*)(pooled + NGRAPH * CDIM);
  auto align256 = [&](char*& q) {
    size_t a = (size_t)(q - (char*)d_ws);
    a = (a + 255) & ~(size_t)255;
    q = (char*)d_ws + a;
  };
  align256(p);
  int* degsum = (int*)p;          p += (size_t)NN * 4;       align256(p);
  int* offs = (int*)p;            p += (size_t)(NN + 1) * 4; align256(p);
  int* cursor8 = (int*)p;         p += (size_t)8 * NN * 4;   align256(p);
  int* esrc = (int*)p;            p += (size_t)(NE + 16 * NN) * 4; align256(p);
  int* bsum = (int*)p;            p += 256 * 4;              align256(p);
  unsigned short* h1 = (unsigned short*)p;   p += (size_t)NN * HC * 2;          align256(p);
  unsigned short* out1 = (unsigned short*)p; p += (size_t)NN * HC * 2;          align256(p);
  unsigned short* h2 = (unsigned short*)p;   p += (size_t)(NN + 1) * CDIM * 2;  align256(p);
  float* als1 = (float*)p;        p += (size_t)(NN + 1) * NHEAD * 4; align256(p);
  float* ald1 = (float*)p;        p += (size_t)NN * NHEAD * 4;       align256(p);
  float* als2v = (float*)p;       p += (size_t)(NN + 1) * 4;         align256(p);
  float* ald2v = (float*)p;       p += (size_t)NN * 4;               align256(p);
  unsigned char* h1f8 = (unsigned char*)p; p += (size_t)(NN + 1) * HC;  align256(p);
  unsigned char* h2f8 = (unsigned char*)p; p += (size_t)(NN + 1) * CDIM; align256(p);
  unsigned short* W1p = (unsigned short*)p; p += 32768 * 2;    align256(p);
  unsigned short* W2p = (unsigned short*)p; p += 16384 * 2;    align256(p);

  zero_kernel<<<(ZWORDS + 255) / 256, 256, 0, stream>>>((int*)d_ws, ZWORDS);
  repack_kernel<<<192, 256, 0, stream>>>(W1, W2, W1p, W2p, als1, als2v, h1f8, h2, h2f8);
  gemm1_kernel<<<(NT1 + 3) / 4, 256, 0, stream>>>(x, W1p, a_src1, a_dst1, h1, h1f8,
                                                  als1, ald1);
  hist_kernel<<<(NE + 255) / 256, 256, 0, stream>>>(edge_index, deg8);
  scan_a<<<NB, 256, 0, stream>>>(deg8, bsum, degsum);
  scan_c<<<NB, 256, 0, stream>>>(degsum, deg8, bsum, offs, cursor8, esrc);
  scatter_kernel<<<2048, 256, 0, stream>>>(edge_index, cursor8, esrc);
  agg1_kernel<<<NN / 4, 256, 0, stream>>>(h1, h1f8, als1, ald1, offs, esrc, b1, out1);
  bnstats_kernel<<<1024, 256, 0, stream>>>(out1, bnsum, bnsumsq);
  gemm2_kernel<<<(NT1 + 3) / 4, 256, 0, stream>>>(out1, W2p, bnsum, bnsumsq, gamma, beta,
                                                  a_src2, a_dst2, h2, h2f8, als2v, ald2v);
  agg2_kernel<<<NN / 4, 256, 0, stream>>>(h2, h2f8, als2v, ald2v, offs, esrc, b2,
                                          batch, pooled);
  cls_kernel<<<NGRAPH, 64, 0, stream>>>(pooled, batch, cW1, cb1, cW2, cb2, (float*)d_out);
}

// Round 10
// 316.827 us; speedup vs baseline: 1.0139x; 1.0139x over previous
//
#include <hip/hip_runtime.h>
#include <hip/hip_bf16.h>
#include <hip/hip_fp8.h>

#define NN 50000
#define NE 800000
#define DIN 128
#define HC 256
#define NHEAD 4
#define CDIM 64
#define NGRAPH 512
#define NCLS 10
#define NEG_SLOPE 0.2f
#define NB 196   // ceil(NN/256)
#define NT1 3125 // NN/16 M-tiles

typedef __hip_bfloat16 bf16;
typedef __attribute__((ext_vector_type(8))) short short8;
typedef __attribute__((ext_vector_type(4))) float f32x4;
typedef __attribute__((ext_vector_type(2))) float f32x2;

__device__ __forceinline__ float bf2f(unsigned short u) {
  union { unsigned int i; float f; } x;
  x.i = ((unsigned int)u) << 16;
  return x.f;
}
__device__ __forceinline__ unsigned short f2bf(float f) {
  bf16 v = __float2bfloat16(f);
  union { bf16 b; unsigned short s; } x;
  x.b = v;
  return x.s;
}
// fp8 e4m3 (OCP) encode/decode via HIP type
__device__ __forceinline__ unsigned char f2f8(float f) {
  __hip_fp8_e4m3 q(f);
  return (unsigned char)q.__x;
}
__device__ __forceinline__ float lrelu(float x) { return x >= 0.f ? x : NEG_SLOPE * x; }
// NaN-propagating relu (fmaxf would silently clamp NaN to 0)
__device__ __forceinline__ float relu(float x) { return x < 0.f ? 0.f : x; }

// ---------------- zero scratch accumulators ----------------
__global__ void zero_kernel(int* __restrict__ p, int n) {
  int i = blockIdx.x * 256 + threadIdx.x;
  if (i < n) p[i] = 0;
}

// ---------------- repack W1,W2 into MFMA B-frag bf16 order + sentinel init ----------
// Sentinel: pad edges point to node NN; als[NN]=-1e30 -> w==0; payload rows NN zeroed.
__global__ void repack_kernel(const float* __restrict__ W1, const float* __restrict__ W2,
                              unsigned short* __restrict__ W1p, unsigned short* __restrict__ W2p,
                              float* __restrict__ als1, float* __restrict__ als2v,
                              unsigned char* __restrict__ h1f8, unsigned short* __restrict__ h2,
                              unsigned char* __restrict__ h2f8) {
  if (blockIdx.x == 0) {
    int t = threadIdx.x;
    if (t < NHEAD) als1[NN * NHEAD + t] = -1e30f;
    if (t == NHEAD) als2v[NN] = -1e30f;
    if (t < 64) ((unsigned int*)(h1f8 + (size_t)NN * HC))[t] = 0u;
    if (t < 32) ((unsigned int*)(h2 + (size_t)NN * CDIM))[t] = 0u;
    if (t < 16) ((unsigned int*)(h2f8 + (size_t)NN * CDIM))[t] = 0u;
  }
  int i = blockIdx.x * 256 + threadIdx.x;
  if (i < 16 * 4 * 64 * 8) {  // W1: [128,256] -> ng(16) kk(4) lane(64) j(8)
    int j = i & 7, lane = (i >> 3) & 63, kk = (i >> 9) & 3, ng = i >> 11;
    int n = ng * 16 + (lane & 15);
    int k = kk * 32 + (lane >> 4) * 8 + j;
    W1p[i] = f2bf(W1[k * HC + n]);
  }
  int i2 = i - 16 * 4 * 64 * 8;
  if (i2 >= 0 && i2 < 4 * 8 * 64 * 8) {  // W2: [256,64] -> ng(4) kk(8) lane(64) j(8)
    int j = i2 & 7, lane = (i2 >> 3) & 63, kk = (i2 >> 9) & 7, ng = i2 >> 12;
    int n = ng * 16 + (lane & 15);
    int k = kk * 32 + (lane >> 4) * 8 + j;
    W2p[i2] = f2bf(W2[k * CDIM + n]);
  }
}

// ---------------- edge histogram (deg by dst, 8-way sharded by e&7) ----------------
__global__ void hist_kernel(const int* __restrict__ ei, int* __restrict__ deg8) {
  int i = blockIdx.x * 256 + threadIdx.x;
  if (i < NE) atomicAdd(&deg8[(i & 7) * NN + ei[NE + i]], 1);
}

// ---------------- exclusive scan of 4-PADDED deg -> off, sharded cursors -------------
__global__ void scan_a(const int* __restrict__ deg8, int* __restrict__ bsum,
                       int* __restrict__ degsum) {
  __shared__ int sm[256];
  int t = threadIdx.x, i = blockIdx.x * 256 + t;
  int d = 0;
  if (i < NN) {
#pragma unroll
    for (int j = 0; j < 8; j++) d += deg8[j * NN + i];
  }
  int dp = (d + 3) & ~3;
  if (i < NN) degsum[i] = dp;
  sm[t] = dp;
  __syncthreads();
  for (int s = 128; s > 0; s >>= 1) {
    if (t < s) sm[t] += sm[t + s];
    __syncthreads();
  }
  if (t == 0) bsum[blockIdx.x] = sm[0];
}
// scan_c also performs scan_b's job: every block redundantly scans the 196
// block-sums in LDS (cheap) -- saves a kernel launch + dependency bubble.
__global__ void scan_c(const int* __restrict__ degsum, const int* __restrict__ deg8,
                       const int* __restrict__ bsum,
                       int* __restrict__ off, int* __restrict__ cursor8,
                       int* __restrict__ esrc) {
  __shared__ int sm[256];
  __shared__ int pre[256];
  int t = threadIdx.x, i = blockIdx.x * 256 + t;
  int own = (t < NB) ? bsum[t] : 0;
  sm[t] = own;
  pre[t] = own;
  __syncthreads();
  for (int s = 1; s < 256; s <<= 1) {
    int v = (t >= s) ? sm[t - s] : 0;
    __syncthreads();
    sm[t] += v;
    __syncthreads();
  }
  int bbase = sm[blockIdx.x] - pre[blockIdx.x];  // exclusive prefix of block sums
  __syncthreads();
  int dp = (i < NN) ? degsum[i] : 0;
  sm[t] = dp;
  __syncthreads();
  for (int s = 1; s < 256; s <<= 1) {
    int v = (t >= s) ? sm[t - s] : 0;
    __syncthreads();
    sm[t] += v;
    __syncthreads();
  }
  int excl = bbase + sm[t] - dp;
  if (i < NN) {
    off[i] = excl;
    int base = excl;
#pragma unroll
    for (int j = 0; j < 8; j++) {
      cursor8[j * NN + i] = base;
      base += deg8[j * NN + i];
    }
    // fill pad slots (at most 3) with the sentinel src (weight == 0, zero payload)
    for (int q = base; q < excl + dp; q++) esrc[q] = NN;
    if (i == NN - 1) off[NN] = excl + dp;
  }
}

// ---------------- FUSED: XCD-affine scatter (blocks 0..2047) + GEMM1 (rest) ---------
// Measured best config (r8 = 317.4 vs r9 separate = 321.2): scatter is the long pole
// and launches first; gemm1's MFMA blocks fill remaining CU slots; one fewer launch.
// Scatter: block (chunk c, xcd x) writes only edges with dst/6250 == x, so each CSR
// line is written by one XCD. GEMM1 also emits the fp8 shadow + fused als1/ald1.
__global__ __launch_bounds__(256) void scatgemm1_kernel(
    const int* __restrict__ ei, int* __restrict__ cursor8, int* __restrict__ esrc,
    const float* __restrict__ x, const unsigned short* __restrict__ W1p,
    const float* __restrict__ a_src, const float* __restrict__ a_dst,
    unsigned short* __restrict__ h1, unsigned char* __restrict__ h1f8,
    float* __restrict__ als, float* __restrict__ ald) {
  __shared__ float sh_as[HC], sh_ad[HC];
  if (blockIdx.x < 2048) {
    int xcd = blockIdx.x & 7;
    int chunk = blockIdx.x >> 3;
    int lo = chunk * (NE / 256);
    int hi = lo + (NE / 256);
    for (int e = lo + threadIdx.x; e < hi; e += 256) {
      int d = ei[NE + e];
      if (d / (NN / 8) == xcd) {
        int s = ei[e];
        int p = atomicAdd(&cursor8[(e & 7) * NN + d], 1);
        esrc[p] = s;
      }
    }
    return;
  }
  {
    int t = threadIdx.x;
    sh_as[t] = a_src[t];
    sh_ad[t] = a_dst[t];
  }
  __syncthreads();
  int wave = threadIdx.x >> 6, lane = threadIdx.x & 63;
  int tile = (blockIdx.x - 2048) * 4 + wave;
  if (tile >= NT1) return;
  int r0 = tile * 16, m = lane & 15, quad = lane >> 4;
  int row = r0 + m;
  short8 a[4];
#pragma unroll
  for (int kk = 0; kk < 4; kk++) {
    int kb = kk * 32 + quad * 8;
    float4 f0 = *(const float4*)(x + row * DIN + kb);
    float4 f1 = *(const float4*)(x + row * DIN + kb + 4);
    alignas(16) unsigned short tmp[8];
    tmp[0] = f2bf(f0.x); tmp[1] = f2bf(f0.y); tmp[2] = f2bf(f0.z); tmp[3] = f2bf(f0.w);
    tmp[4] = f2bf(f1.x); tmp[5] = f2bf(f1.y); tmp[6] = f2bf(f1.z); tmp[7] = f2bf(f1.w);
    a[kk] = *(const short8*)tmp;
  }
#pragma unroll
  for (int hg = 0; hg < 4; hg++) {
    float ps[4] = {0.f, 0.f, 0.f, 0.f};
    float pd[4] = {0.f, 0.f, 0.f, 0.f};
#pragma unroll
    for (int sub = 0; sub < 4; sub++) {
      int ng = hg * 4 + sub;
      f32x4 acc = {0.f, 0.f, 0.f, 0.f};
#pragma unroll
      for (int kk = 0; kk < 4; kk++) {
        short8 b = *(const short8*)(W1p + ((ng * 4 + kk) * 64 + lane) * 8);
        acc = __builtin_amdgcn_mfma_f32_16x16x32_bf16(a[kk], b, acc, 0, 0, 0);
      }
      int col = ng * 16 + m;
      float asv = sh_as[col], adv = sh_ad[col];
#pragma unroll
      for (int r = 0; r < 4; r++) {
        int rr = r0 + quad * 4 + r;
        h1[rr * HC + col] = f2bf(acc[r]);
        h1f8[rr * HC + col] = f2f8(acc[r]);
        ps[r] += acc[r] * asv;
        pd[r] += acc[r] * adv;
      }
    }
#pragma unroll
    for (int o = 1; o < 16; o <<= 1) {
#pragma unroll
      for (int r = 0; r < 4; r++) {
        ps[r] += __shfl_xor(ps[r], o, 64);
        pd[r] += __shfl_xor(pd[r], o, 64);
      }
    }
    if (m == 0) {
#pragma unroll
      for (int r = 0; r < 4; r++) {
        int rr = r0 + quad * 4 + r;
        als[rr * NHEAD + hg] = ps[r];
        ald[rr * NHEAD + hg] = pd[r];
      }
    }
  }
}

// ---------------- GAT layer1 aggregation: wave/node, fp8 packed decode ---------------
// 2 edge-groups x 32 lanes x 8 fp8 channels, 8 gathers in flight, sentinel-padded
// CSR (no tail clamps). 4-padded rows: 16-slot main chunks + optional 8-slot
// half-chunk + optional 4-slot quarter-chunk (pad waste +22% -> +11%).
__global__ __launch_bounds__(256) void agg1_kernel(const unsigned short* __restrict__ h1,
                                                   const unsigned char* __restrict__ h1f8,
                                                   const float* __restrict__ als,
                                                   const float* __restrict__ ald,
                                                   const int* __restrict__ off,
                                                   const int* __restrict__ esrc,
                                                   const float* __restrict__ b1,
                                                   unsigned short* __restrict__ out1) {
  int node = blockIdx.x * 4 + (threadIdx.x >> 6);
  int lane = threadIdx.x & 63;
  int eg = lane >> 5;
  int c0 = (lane & 31) * 8;
  int hh = c0 >> 6;
  int beg = off[node], end = off[node + 1];
  float aldh = ald[node * NHEAD + hh];
  float a[8] = {0.f, 0.f, 0.f, 0.f, 0.f, 0.f, 0.f, 0.f};
  float zz = 0.f;
  int k = beg;
  for (; k + 16 <= end; k += 16) {
    int s[8];
    float w[8];
    uint2 u[8];
#pragma unroll
    for (int j = 0; j < 8; j++) s[j] = esrc[k + 2 * j + eg];
#pragma unroll
    for (int j = 0; j < 8; j++) {
      w[j] = __expf(lrelu(als[s[j] * NHEAD + hh] + aldh));
      u[j] = *(const uint2*)(h1f8 + s[j] * HC + c0);
    }
#pragma unroll
    for (int j = 0; j < 8; j++) {
      f32x2 p0 = __builtin_amdgcn_cvt_pk_f32_fp8(u[j].x, false);
      f32x2 p1 = __builtin_amdgcn_cvt_pk_f32_fp8(u[j].x, true);
      f32x2 p2 = __builtin_amdgcn_cvt_pk_f32_fp8(u[j].y, false);
      f32x2 p3 = __builtin_amdgcn_cvt_pk_f32_fp8(u[j].y, true);
      a[0] += w[j] * p0.x; a[1] += w[j] * p0.y;
      a[2] += w[j] * p1.x; a[3] += w[j] * p1.y;
      a[4] += w[j] * p2.x; a[5] += w[j] * p2.y;
      a[6] += w[j] * p3.x; a[7] += w[j] * p3.y;
      zz += w[j];
    }
  }
  if (k + 8 <= end) {  // 8-slot half-chunk
    int s[4];
    float w[4];
    uint2 u[4];
#pragma unroll
    for (int j = 0; j < 4; j++) s[j] = esrc[k + 2 * j + eg];
#pragma unroll
    for (int j = 0; j < 4; j++) {
      w[j] = __expf(lrelu(als[s[j] * NHEAD + hh] + aldh));
      u[j] = *(const uint2*)(h1f8 + s[j] * HC + c0);
    }
#pragma unroll
    for (int j = 0; j < 4; j++) {
      f32x2 p0 = __builtin_amdgcn_cvt_pk_f32_fp8(u[j].x, false);
      f32x2 p1 = __builtin_amdgcn_cvt_pk_f32_fp8(u[j].x, true);
      f32x2 p2 = __builtin_amdgcn_cvt_pk_f32_fp8(u[j].y, false);
      f32x2 p3 = __builtin_amdgcn_cvt_pk_f32_fp8(u[j].y, true);
      a[0] += w[j] * p0.x; a[1] += w[j] * p0.y;
      a[2] += w[j] * p1.x; a[3] += w[j] * p1.y;
      a[4] += w[j] * p2.x; a[5] += w[j] * p2.y;
      a[6] += w[j] * p3.x; a[7] += w[j] * p3.y;
      zz += w[j];
    }
    k += 8;
  }
  if (k < end) {  // 4-slot quarter-chunk
    int s[2];
    float w[2];
    uint2 u[2];
#pragma unroll
    for (int j = 0; j < 2; j++) s[j] = esrc[k + 2 * j + eg];
#pragma unroll
    for (int j = 0; j < 2; j++) {
      w[j] = __expf(lrelu(als[s[j] * NHEAD + hh] + aldh));
      u[j] = *(const uint2*)(h1f8 + s[j] * HC + c0);
    }
#pragma unroll
    for (int j = 0; j < 2; j++) {
      f32x2 p0 = __builtin_amdgcn_cvt_pk_f32_fp8(u[j].x, false);
      f32x2 p1 = __builtin_amdgcn_cvt_pk_f32_fp8(u[j].x, true);
      f32x2 p2 = __builtin_amdgcn_cvt_pk_f32_fp8(u[j].y, false);
      f32x2 p3 = __builtin_amdgcn_cvt_pk_f32_fp8(u[j].y, true);
      a[0] += w[j] * p0.x; a[1] += w[j] * p0.y;
      a[2] += w[j] * p1.x; a[3] += w[j] * p1.y;
      a[4] += w[j] * p2.x; a[5] += w[j] * p2.y;
      a[6] += w[j] * p3.x; a[7] += w[j] * p3.y;
      zz += w[j];
    }
  }
  // combine the two edge-groups (lanes L and L^32 cover the same channels)
#pragma unroll
  for (int j = 0; j < 8; j++) a[j] += __shfl_xor(a[j], 32, 64);
  zz += __shfl_xor(zz, 32, 64);
  if (eg == 0) {
    // self-loop from bf16 original
    float sw = __expf(lrelu(als[node * NHEAD + hh] + aldh));
    ushort4 vs0 = *(const ushort4*)(h1 + node * HC + c0);
    ushort4 vs1 = *(const ushort4*)(h1 + node * HC + c0 + 4);
    a[0] += sw * bf2f(vs0.x); a[1] += sw * bf2f(vs0.y);
    a[2] += sw * bf2f(vs0.z); a[3] += sw * bf2f(vs0.w);
    a[4] += sw * bf2f(vs1.x); a[5] += sw * bf2f(vs1.y);
    a[6] += sw * bf2f(vs1.z); a[7] += sw * bf2f(vs1.w);
    zz += sw;
    float inv = 1.f / zz;
    float4 bb0 = *(const float4*)(b1 + c0);
    float4 bb1 = *(const float4*)(b1 + c0 + 4);
    ushort4 o0, o1;
    o0.x = f2bf(a[0] * inv + bb0.x); o0.y = f2bf(a[1] * inv + bb0.y);
    o0.z = f2bf(a[2] * inv + bb0.z); o0.w = f2bf(a[3] * inv + bb0.w);
    o1.x = f2bf(a[4] * inv + bb1.x); o1.y = f2bf(a[5] * inv + bb1.y);
    o1.z = f2bf(a[6] * inv + bb1.z); o1.w = f2bf(a[7] * inv + bb1.w);
    *(ushort4*)(out1 + node * HC + c0) = o0;
    *(ushort4*)(out1 + node * HC + c0 + 4) = o1;
  }
}

// ---------------- BN stats over out1 ----------------
__global__ __launch_bounds__(256) void bnstats_kernel(const unsigned short* __restrict__ out1,
                                                      float* __restrict__ bnsum,
                                                      float* __restrict__ bnsumsq) {
  int t = threadIdx.x;
  float s = 0.f, s2 = 0.f;
  for (int r = blockIdx.x; r < NN; r += gridDim.x) {
    float v = bf2f(out1[r * HC + t]);
    s += v;
    s2 += v * v;
  }
  atomicAdd(&bnsum[t], s);
  atomicAdd(&bnsumsq[t], s2);
}

// ---------------- GEMM2 + fused als2/ald2 + fp8 shadow: h2 = relu(bn(out1)) @ W2 -----
__global__ __launch_bounds__(256) void gemm2_kernel(const unsigned short* __restrict__ out1,
                                                    const unsigned short* __restrict__ W2p,
                                                    const float* __restrict__ bnsum,
                                                    const float* __restrict__ bnsumsq,
                                                    const float* __restrict__ gamma,
                                                    const float* __restrict__ beta,
                                                    const float* __restrict__ a_src2,
                                                    const float* __restrict__ a_dst2,
                                                    unsigned short* __restrict__ h2,
                                                    unsigned char* __restrict__ h2f8,
                                                    float* __restrict__ als2,
                                                    float* __restrict__ ald2) {
  __shared__ float scale_s[HC], shift_s[HC];
  __shared__ float sh_as[CDIM], sh_ad[CDIM];
  {
    int t = threadIdx.x;
    float mu = bnsum[t] / (float)NN;
    float var = bnsumsq[t] / (float)NN - mu * mu;
    float sc = gamma[t] * rsqrtf(var + 1e-5f);
    scale_s[t] = sc;
    shift_s[t] = beta[t] - mu * sc;
    if (t < CDIM) {
      sh_as[t] = a_src2[t];
      sh_ad[t] = a_dst2[t];
    }
  }
  __syncthreads();
  int wave = threadIdx.x >> 6, lane = threadIdx.x & 63;
  int tile = blockIdx.x * 4 + wave;
  if (tile >= NT1) return;
  int r0 = tile * 16, m = lane & 15, quad = lane >> 4;
  int row = r0 + m;
  short8 a[8];
#pragma unroll
  for (int kk = 0; kk < 8; kk++) {
    int kb = kk * 32 + quad * 8;
    short8 raw = *(const short8*)(out1 + row * HC + kb);
    alignas(16) unsigned short tmp[8];
#pragma unroll
    for (int j = 0; j < 8; j++) {
      tmp[j] = f2bf(relu(bf2f((unsigned short)raw[j]) * scale_s[kb + j] + shift_s[kb + j]));
    }
    a[kk] = *(const short8*)tmp;
  }
  float ps[4] = {0.f, 0.f, 0.f, 0.f};
  float pd[4] = {0.f, 0.f, 0.f, 0.f};
#pragma unroll
  for (int ng = 0; ng < 4; ng++) {
    f32x4 acc = {0.f, 0.f, 0.f, 0.f};
#pragma unroll
    for (int kk = 0; kk < 8; kk++) {
      short8 b = *(const short8*)(W2p + ((ng * 8 + kk) * 64 + lane) * 8);
      acc = __builtin_amdgcn_mfma_f32_16x16x32_bf16(a[kk], b, acc, 0, 0, 0);
    }
    int col = ng * 16 + m;
    float asv = sh_as[col], adv = sh_ad[col];
#pragma unroll
    for (int r = 0; r < 4; r++) {
      int rr = r0 + quad * 4 + r;
      h2[rr * CDIM + col] = f2bf(acc[r]);
      h2f8[rr * CDIM + col] = f2f8(acc[r]);
      ps[r] += acc[r] * asv;
      pd[r] += acc[r] * adv;
    }
  }
#pragma unroll
  for (int o = 1; o < 16; o <<= 1) {
#pragma unroll
    for (int r = 0; r < 4; r++) {
      ps[r] += __shfl_xor(ps[r], o, 64);
      pd[r] += __shfl_xor(pd[r], o, 64);
    }
  }
  if (m == 0) {
#pragma unroll
    for (int r = 0; r < 4; r++) {
      int rr = r0 + quad * 4 + r;
      als2[rr] = ps[r];
      ald2[rr] = pd[r];
    }
  }
}

// ---------------- GAT layer2 agg + ReLU + pooling ----------------
// 4 edge-groups x 16 lanes x 4 fp8 channels (uint gathers into the 3.2MB L2-resident
// h2f8 table; bf16 self-loop keeps precision). 4-padded CSR: 16-slot main chunks +
// optional 8-slot half-chunk + optional 4-slot quarter-chunk. Pooled atomics
// block-combined in LDS.
__global__ __launch_bounds__(256) void agg2_kernel(const unsigned short* __restrict__ h2,
                                                   const unsigned char* __restrict__ h2f8,
                                                   const float* __restrict__ als2,
                                                   const float* __restrict__ ald2,
                                                   const int* __restrict__ off,
                                                   const int* __restrict__ esrc,
                                                   const float* __restrict__ b2,
                                                   const int* __restrict__ batch,
                                                   float* __restrict__ pooled) {
  __shared__ float svv[4][CDIM];
  __shared__ int sg[4];
  int wave = threadIdx.x >> 6;
  int node = blockIdx.x * 4 + wave;
  int lane = threadIdx.x & 63;
  int eg = lane >> 4;          // 4 edge groups
  int cp = (lane & 15) * 4;    // 4 channels per lane
  int beg = off[node], end = off[node + 1];
  float aldn = ald2[node];
  float a0 = 0.f, a1 = 0.f, a2 = 0.f, a3 = 0.f, zz = 0.f;
  int k = beg;
  for (; k + 16 <= end; k += 16) {
    int s[4];
    float w[4];
    unsigned int u[4];
#pragma unroll
    for (int j = 0; j < 4; j++) s[j] = esrc[k + 4 * j + eg];
#pragma unroll
    for (int j = 0; j < 4; j++) {
      w[j] = __expf(lrelu(als2[s[j]] + aldn));
      u[j] = *(const unsigned int*)(h2f8 + s[j] * CDIM + cp);
    }
#pragma unroll
    for (int j = 0; j < 4; j++) {
      f32x2 p0 = __builtin_amdgcn_cvt_pk_f32_fp8(u[j], false);
      f32x2 p1 = __builtin_amdgcn_cvt_pk_f32_fp8(u[j], true);
      a0 += w[j] * p0.x;
      a1 += w[j] * p0.y;
      a2 += w[j] * p1.x;
      a3 += w[j] * p1.y;
      zz += w[j];
    }
  }
  if (k + 8 <= end) {  // 8-slot half-chunk
    int s[2];
    float w[2];
    unsigned int u[2];
#pragma unroll
    for (int j = 0; j < 2; j++) s[j] = esrc[k + 4 * j + eg];
#pragma unroll
    for (int j = 0; j < 2; j++) {
      w[j] = __expf(lrelu(als2[s[j]] + aldn));
      u[j] = *(const unsigned int*)(h2f8 + s[j] * CDIM + cp);
    }
#pragma unroll
    for (int j = 0; j < 2; j++) {
      f32x2 p0 = __builtin_amdgcn_cvt_pk_f32_fp8(u[j], false);
      f32x2 p1 = __builtin_amdgcn_cvt_pk_f32_fp8(u[j], true);
      a0 += w[j] * p0.x;
      a1 += w[j] * p0.y;
      a2 += w[j] * p1.x;
      a3 += w[j] * p1.y;
      zz += w[j];
    }
    k += 8;
  }
  if (k < end) {  // 4-slot quarter-chunk
    int s0 = esrc[k + eg];
    float w0 = __expf(lrelu(als2[s0] + aldn));
    unsigned int u0 = *(const unsigned int*)(h2f8 + s0 * CDIM + cp);
    f32x2 p0 = __builtin_amdgcn_cvt_pk_f32_fp8(u0, false);
    f32x2 p1 = __builtin_amdgcn_cvt_pk_f32_fp8(u0, true);
    a0 += w0 * p0.x;
    a1 += w0 * p0.y;
    a2 += w0 * p1.x;
    a3 += w0 * p1.y;
    zz += w0;
  }
  // combine the four edge-groups (lanes sharing (lane&15) cover same channels)
  a0 += __shfl_xor(a0, 16, 64); a0 += __shfl_xor(a0, 32, 64);
  a1 += __shfl_xor(a1, 16, 64); a1 += __shfl_xor(a1, 32, 64);
  a2 += __shfl_xor(a2, 16, 64); a2 += __shfl_xor(a2, 32, 64);
  a3 += __shfl_xor(a3, 16, 64); a3 += __shfl_xor(a3, 32, 64);
  zz += __shfl_xor(zz, 16, 64); zz += __shfl_xor(zz, 32, 64);
  if (eg == 0) {
    float sw = __expf(lrelu(als2[node] + aldn));
    ushort4 vs = *(const ushort4*)(h2 + node * CDIM + cp);
    a0 += sw * bf2f(vs.x);
    a1 += sw * bf2f(vs.y);
    a2 += sw * bf2f(vs.z);
    a3 += sw * bf2f(vs.w);
    zz += sw;
    float inv = 1.f / zz;
    float4 bb = *(const float4*)(b2 + cp);
    svv[wave][cp + 0] = relu(a0 * inv + bb.x);
    svv[wave][cp + 1] = relu(a1 * inv + bb.y);
    svv[wave][cp + 2] = relu(a2 * inv + bb.z);
    svv[wave][cp + 3] = relu(a3 * inv + bb.w);
    if (lane == 0) sg[wave] = batch[node];
  }
  __syncthreads();
  int t = threadIdx.x;
  if (t < CDIM) {
    int g0 = sg[0], g1 = sg[1], g2 = sg[2], g3 = sg[3];
#pragma unroll
    for (int w = 0; w < 4; w++) {
      int gs[4] = {g0, g1, g2, g3};
      int gw = gs[w];
      bool first = true;
#pragma unroll
      for (int w2 = 0; w2 < 4; w2++)
        if (w2 < w && gs[w2] == gw) first = false;
      if (first) {
        float acc = svv[w][t];
#pragma unroll
        for (int w2 = 0; w2 < 4; w2++)
          if (w2 > w && gs[w2] == gw) acc += svv[w2][t];
        atomicAdd(&pooled[gw * CDIM + t], acc);
      }
    }
  }
}

// ---------------- pooled mean + classifier (f32 output); counts via binary search ----
__global__ void cls_kernel(const float* __restrict__ pooled, const int* __restrict__ batch,
                           const float* __restrict__ cW1, const float* __restrict__ cb1,
                           const float* __restrict__ cW2, const float* __restrict__ cb2,
                           float* __restrict__ out) {
  __shared__ float p[64];
  __shared__ float z[32];
  int g = blockIdx.x, t = threadIdx.x;
  int lo = 0, hi = NN;
  while (lo < hi) { int mid = (lo + hi) >> 1; if (batch[mid] < g) lo = mid + 1; else hi = mid; }
  int start = lo;
  lo = 0; hi = NN;
  while (lo < hi) { int mid = (lo + hi) >> 1; if (batch[mid] <= g) lo = mid + 1; else hi = mid; }
  int c = lo - start;
  float cnt = (float)(c > 0 ? c : 1);
  p[t] = pooled[g * CDIM + t] / cnt;
  __syncthreads();
  if (t < 32) {
    float a = cb1[t];
    for (int k = 0; k < 64; k++) a += p[k] * cW1[k * 32 + t];
    z[t] = relu(a);
  }
  __syncthreads();
  if (t < NCLS) {
    float a = cb2[t];
    for (int k = 0; k < 32; k++) a += z[k] * cW2[k * NCLS + t];
    out[g * NCLS + t] = a;
  }
}

extern "C" void kernel_launch(void* const* d_in, const int* in_sizes, int n_in,
                              void* d_out, int out_size, void* d_ws, size_t ws_size,
                              hipStream_t stream) {
  const float* x = (const float*)d_in[0];
  const int* edge_index = (const int*)d_in[1];
  const int* batch = (const int*)d_in[2];
  const float* W1 = (const float*)d_in[3];
  const float* a_src1 = (const float*)d_in[4];
  const float* a_dst1 = (const float*)d_in[5];
  const float* b1 = (const float*)d_in[6];
  const float* gamma = (const float*)d_in[7];
  const float* beta = (const float*)d_in[8];
  const float* W2 = (const float*)d_in[9];
  const float* a_src2 = (const float*)d_in[10];
  const float* a_dst2 = (const float*)d_in[11];
  const float* b2 = (const float*)d_in[12];
  const float* cW1 = (const float*)d_in[13];
  const float* cb1 = (const float*)d_in[14];
  const float* cW2 = (const float*)d_in[15];
  const float* cb2 = (const float*)d_in[16];

  // ---- workspace layout ----
  // zero region (contiguous, zeroed every call): deg8 | bnsum | bnsumsq | pooled
  int* deg8 = (int*)d_ws;
  float* bnsum = (float*)(deg8 + 8 * NN);
  float* bnsumsq = bnsum + HC;
  float* pooled = bnsumsq + HC;
  const int ZWORDS = 8 * NN + HC + HC + NGRAPH * CDIM;
  char* p = (char*)(pooled + NGRAPH * CDIM);
  auto align256 = [&](char*& q) {
    size_t a = (size_t)(q - (char*)d_ws);
    a = (a + 255) & ~(size_t)255;
    q = (char*)d_ws + a;
  };
  align256(p);
  int* degsum = (int*)p;          p += (size_t)NN * 4;       align256(p);
  int* offs = (int*)p;            p += (size_t)(NN + 1) * 4; align256(p);
  int* cursor8 = (int*)p;         p += (size_t)8 * NN * 4;   align256(p);
  int* esrc = (int*)p;            p += (size_t)(NE + 16 * NN) * 4; align256(p);
  int* bsum = (int*)p;            p += 256 * 4;              align256(p);
  unsigned short* h1 = (unsigned short*)p;   p += (size_t)NN * HC * 2;          align256(p);
  unsigned short* out1 = (unsigned short*)p; p += (size_t)NN * HC * 2;          align256(p);
  unsigned short* h2 = (unsigned short*)p;   p += (size_t)(NN + 1) * CDIM * 2;  align256(p);
  float* als1 = (float*)p;        p += (size_t)(NN + 1) * NHEAD * 4; align256(p);
  float* ald1 = (float*)p;        p += (size_t)NN * NHEAD * 4;       align256(p);
  float* als2v = (float*)p;       p += (size_t)(NN + 1) * 4;         align256(p);
  float* ald2v = (float*)p;       p += (size_t)NN * 4;               align256(p);
  unsigned char* h1f8 = (unsigned char*)p; p += (size_t)(NN + 1) * HC;  align256(p);
  unsigned char* h2f8 = (unsigned char*)p; p += (size_t)(NN + 1) * CDIM; align256(p);
  unsigned short* W1p = (unsigned short*)p; p += 32768 * 2;    align256(p);
  unsigned short* W2p = (unsigned short*)p; p += 16384 * 2;    align256(p);

  zero_kernel<<<(ZWORDS + 255) / 256, 256, 0, stream>>>((int*)d_ws, ZWORDS);
  repack_kernel<<<192, 256, 0, stream>>>(W1, W2, W1p, W2p, als1, als2v, h1f8, h2, h2f8);
  hist_kernel<<<(NE + 255) / 256, 256, 0, stream>>>(edge_index, deg8);
  scan_a<<<NB, 256, 0, stream>>>(deg8, bsum, degsum);
  scan_c<<<NB, 256, 0, stream>>>(degsum, deg8, bsum, offs, cursor8, esrc);
  scatgemm1_kernel<<<2048 + (NT1 + 3) / 4, 256, 0, stream>>>(
      edge_index, cursor8, esrc, x, W1p, a_src1, a_dst1, h1, h1f8, als1, ald1);
  agg1_kernel<<<NN / 4, 256, 0, stream>>>(h1, h1f8, als1, ald1, offs, esrc, b1, out1);
  bnstats_kernel<<<1024, 256, 0, stream>>>(out1, bnsum, bnsumsq);
  gemm2_kernel<<<(NT1 + 3) / 4, 256, 0, stream>>>(out1, W2p, bnsum, bnsumsq, gamma, beta,
                                                  a_src2, a_dst2, h2, h2f8, als2v, ald2v);
  agg2_kernel<<<NN / 4, 256, 0, stream>>>(h2, h2f8, als2v, ald2v, offs, esrc, b2,
                                          batch, pooled);
  cls_kernel<<<NGRAPH, 64, 0, stream>>>(pooled, batch, cW1, cb1, cW2, cb2, (float*)d_out);
}

// Round 11
// 287.039 us; speedup vs baseline: 1.1191x; 1.1038x over previous
//
#include <hip/hip_runtime.h>
#include <hip/hip_bf16.h>
#include <hip/hip_fp8.h>

#define NN 50000
#define NE 800000
#define DIN 128
#define HC 256
#define NHEAD 4
#define CDIM 64
#define NGRAPH 512
#define NCLS 10
#define NEG_SLOPE 0.2f
#define NB 196   // ceil(NN/256)
#define NT1 3125 // NN/16 M-tiles
// zero region words: deg8 | bnsum8(8*HC) | bnsumsq8(8*HC) | pooled
#define ZWORDS (8 * NN + 8 * HC + 8 * HC + NGRAPH * CDIM)

typedef __hip_bfloat16 bf16;
typedef __attribute__((ext_vector_type(8))) short short8;
typedef __attribute__((ext_vector_type(4))) float f32x4;
typedef __attribute__((ext_vector_type(2))) float f32x2;

__device__ __forceinline__ float bf2f(unsigned short u) {
  union { unsigned int i; float f; } x;
  x.i = ((unsigned int)u) << 16;
  return x.f;
}
__device__ __forceinline__ unsigned short f2bf(float f) {
  bf16 v = __float2bfloat16(f);
  union { bf16 b; unsigned short s; } x;
  x.b = v;
  return x.s;
}
// fp8 e4m3 (OCP) encode/decode via HIP type
__device__ __forceinline__ unsigned char f2f8(float f) {
  __hip_fp8_e4m3 q(f);
  return (unsigned char)q.__x;
}
__device__ __forceinline__ float lrelu(float x) { return x >= 0.f ? x : NEG_SLOPE * x; }
// NaN-propagating relu (fmaxf would silently clamp NaN to 0)
__device__ __forceinline__ float relu(float x) { return x < 0.f ? 0.f : x; }

// ---------------- FUSED zero + repack + sentinel init ----------------
// Zeroes the accumulator region (by global index) and repacks W1/W2 into MFMA
// B-frag bf16 order (i-range-guarded, same indices as before). Sentinel: pad edges
// point to node NN; als[NN]=-1e30 -> w==0; payload rows NN zeroed.
__global__ void repack_kernel(const float* __restrict__ W1, const float* __restrict__ W2,
                              unsigned short* __restrict__ W1p, unsigned short* __restrict__ W2p,
                              float* __restrict__ als1, float* __restrict__ als2v,
                              unsigned char* __restrict__ h1f8, unsigned short* __restrict__ h2,
                              unsigned char* __restrict__ h2f8, int* __restrict__ zp) {
  int i = blockIdx.x * 256 + threadIdx.x;
  if (i < ZWORDS) zp[i] = 0;
  if (blockIdx.x == 0) {
    int t = threadIdx.x;
    if (t < NHEAD) als1[NN * NHEAD + t] = -1e30f;
    if (t == NHEAD) als2v[NN] = -1e30f;
    if (t < 64) ((unsigned int*)(h1f8 + (size_t)NN * HC))[t] = 0u;
    if (t < 32) ((unsigned int*)(h2 + (size_t)NN * CDIM))[t] = 0u;
    if (t < 16) ((unsigned int*)(h2f8 + (size_t)NN * CDIM))[t] = 0u;
  }
  if (i < 16 * 4 * 64 * 8) {  // W1: [128,256] -> ng(16) kk(4) lane(64) j(8)
    int j = i & 7, lane = (i >> 3) & 63, kk = (i >> 9) & 3, ng = i >> 11;
    int n = ng * 16 + (lane & 15);
    int k = kk * 32 + (lane >> 4) * 8 + j;
    W1p[i] = f2bf(W1[k * HC + n]);
  }
  int i2 = i - 16 * 4 * 64 * 8;
  if (i2 >= 0 && i2 < 4 * 8 * 64 * 8) {  // W2: [256,64] -> ng(4) kk(8) lane(64) j(8)
    int j = i2 & 7, lane = (i2 >> 3) & 63, kk = (i2 >> 9) & 7, ng = i2 >> 12;
    int n = ng * 16 + (lane & 15);
    int k = kk * 32 + (lane >> 4) * 8 + j;
    W2p[i2] = f2bf(W2[k * CDIM + n]);
  }
}

// ---------------- edge histogram (deg by dst, 8-way sharded by e&7) ----------------
__global__ void hist_kernel(const int* __restrict__ ei, int* __restrict__ deg8) {
  int i = blockIdx.x * 256 + threadIdx.x;
  if (i < NE) atomicAdd(&deg8[(i & 7) * NN + ei[NE + i]], 1);
}

// ---------------- exclusive scan of 4-PADDED deg -> off, sharded cursors -------------
__global__ void scan_a(const int* __restrict__ deg8, int* __restrict__ bsum,
                       int* __restrict__ degsum) {
  __shared__ int sm[256];
  int t = threadIdx.x, i = blockIdx.x * 256 + t;
  int d = 0;
  if (i < NN) {
#pragma unroll
    for (int j = 0; j < 8; j++) d += deg8[j * NN + i];
  }
  int dp = (d + 3) & ~3;
  if (i < NN) degsum[i] = dp;
  sm[t] = dp;
  __syncthreads();
  for (int s = 128; s > 0; s >>= 1) {
    if (t < s) sm[t] += sm[t + s];
    __syncthreads();
  }
  if (t == 0) bsum[blockIdx.x] = sm[0];
}
// scan_c also performs scan_b's job: every block redundantly scans the 196
// block-sums in LDS (cheap) -- saves a kernel launch + dependency bubble.
__global__ void scan_c(const int* __restrict__ degsum, const int* __restrict__ deg8,
                       const int* __restrict__ bsum,
                       int* __restrict__ off, int* __restrict__ cursor8,
                       int* __restrict__ esrc) {
  __shared__ int sm[256];
  __shared__ int pre[256];
  int t = threadIdx.x, i = blockIdx.x * 256 + t;
  int own = (t < NB) ? bsum[t] : 0;
  sm[t] = own;
  pre[t] = own;
  __syncthreads();
  for (int s = 1; s < 256; s <<= 1) {
    int v = (t >= s) ? sm[t - s] : 0;
    __syncthreads();
    sm[t] += v;
    __syncthreads();
  }
  int bbase = sm[blockIdx.x] - pre[blockIdx.x];  // exclusive prefix of block sums
  __syncthreads();
  int dp = (i < NN) ? degsum[i] : 0;
  sm[t] = dp;
  __syncthreads();
  for (int s = 1; s < 256; s <<= 1) {
    int v = (t >= s) ? sm[t - s] : 0;
    __syncthreads();
    sm[t] += v;
    __syncthreads();
  }
  int excl = bbase + sm[t] - dp;
  if (i < NN) {
    off[i] = excl;
    int base = excl;
#pragma unroll
    for (int j = 0; j < 8; j++) {
      cursor8[j * NN + i] = base;
      base += deg8[j * NN + i];
    }
    // fill pad slots (at most 3) with the sentinel src (weight == 0, zero payload)
    for (int q = base; q < excl + dp; q++) esrc[q] = NN;
    if (i == NN - 1) off[NN] = excl + dp;
  }
}

// ---------------- FUSED: XCD-affine scatter (blocks 0..2047) + GEMM1 (rest) ---------
// Measured best config (r8 = 317.4 vs r9 separate = 321.2): scatter is the long pole
// and launches first; gemm1's MFMA blocks fill remaining CU slots; one fewer launch.
// Scatter: block (chunk c, xcd x) writes only edges with dst/6250 == x, so each CSR
// line is written by one XCD. GEMM1 also emits the fp8 shadow + fused als1/ald1.
__global__ __launch_bounds__(256) void scatgemm1_kernel(
    const int* __restrict__ ei, int* __restrict__ cursor8, int* __restrict__ esrc,
    const float* __restrict__ x, const unsigned short* __restrict__ W1p,
    const float* __restrict__ a_src, const float* __restrict__ a_dst,
    unsigned short* __restrict__ h1, unsigned char* __restrict__ h1f8,
    float* __restrict__ als, float* __restrict__ ald) {
  __shared__ float sh_as[HC], sh_ad[HC];
  if (blockIdx.x < 2048) {
    int xcd = blockIdx.x & 7;
    int chunk = blockIdx.x >> 3;
    int lo = chunk * (NE / 256);
    int hi = lo + (NE / 256);
    for (int e = lo + threadIdx.x; e < hi; e += 256) {
      int d = ei[NE + e];
      if (d / (NN / 8) == xcd) {
        int s = ei[e];
        int p = atomicAdd(&cursor8[(e & 7) * NN + d], 1);
        esrc[p] = s;
      }
    }
    return;
  }
  {
    int t = threadIdx.x;
    sh_as[t] = a_src[t];
    sh_ad[t] = a_dst[t];
  }
  __syncthreads();
  int wave = threadIdx.x >> 6, lane = threadIdx.x & 63;
  int tile = (blockIdx.x - 2048) * 4 + wave;
  if (tile >= NT1) return;
  int r0 = tile * 16, m = lane & 15, quad = lane >> 4;
  int row = r0 + m;
  short8 a[4];
#pragma unroll
  for (int kk = 0; kk < 4; kk++) {
    int kb = kk * 32 + quad * 8;
    float4 f0 = *(const float4*)(x + row * DIN + kb);
    float4 f1 = *(const float4*)(x + row * DIN + kb + 4);
    alignas(16) unsigned short tmp[8];
    tmp[0] = f2bf(f0.x); tmp[1] = f2bf(f0.y); tmp[2] = f2bf(f0.z); tmp[3] = f2bf(f0.w);
    tmp[4] = f2bf(f1.x); tmp[5] = f2bf(f1.y); tmp[6] = f2bf(f1.z); tmp[7] = f2bf(f1.w);
    a[kk] = *(const short8*)tmp;
  }
#pragma unroll
  for (int hg = 0; hg < 4; hg++) {
    float ps[4] = {0.f, 0.f, 0.f, 0.f};
    float pd[4] = {0.f, 0.f, 0.f, 0.f};
#pragma unroll
    for (int sub = 0; sub < 4; sub++) {
      int ng = hg * 4 + sub;
      f32x4 acc = {0.f, 0.f, 0.f, 0.f};
#pragma unroll
      for (int kk = 0; kk < 4; kk++) {
        short8 b = *(const short8*)(W1p + ((ng * 4 + kk) * 64 + lane) * 8);
        acc = __builtin_amdgcn_mfma_f32_16x16x32_bf16(a[kk], b, acc, 0, 0, 0);
      }
      int col = ng * 16 + m;
      float asv = sh_as[col], adv = sh_ad[col];
#pragma unroll
      for (int r = 0; r < 4; r++) {
        int rr = r0 + quad * 4 + r;
        h1[rr * HC + col] = f2bf(acc[r]);
        h1f8[rr * HC + col] = f2f8(acc[r]);
        ps[r] += acc[r] * asv;
        pd[r] += acc[r] * adv;
      }
    }
#pragma unroll
    for (int o = 1; o < 16; o <<= 1) {
#pragma unroll
      for (int r = 0; r < 4; r++) {
        ps[r] += __shfl_xor(ps[r], o, 64);
        pd[r] += __shfl_xor(pd[r], o, 64);
      }
    }
    if (m == 0) {
#pragma unroll
      for (int r = 0; r < 4; r++) {
        int rr = r0 + quad * 4 + r;
        als[rr * NHEAD + hg] = ps[r];
        ald[rr * NHEAD + hg] = pd[r];
      }
    }
  }
}

// ---------------- GAT layer1 aggregation + FUSED BN stats ----------------
// 2 edge-groups x 32 lanes x 8 fp8 channels, 8 gathers in flight, sentinel-padded
// CSR (no tail clamps). 4-padded rows: 16-slot main chunks + optional 8-slot
// half-chunk + optional 4-slot quarter-chunk. BN stats: the eg==0 lanes hold the
// final out1 floats; per-block LDS combine + one 8-way-sharded global atomicAdd per
// channel replaces the old bnstats kernel (saves a full 25.6MB out1 re-read).
__global__ __launch_bounds__(256) void agg1_kernel(const unsigned short* __restrict__ h1,
                                                   const unsigned char* __restrict__ h1f8,
                                                   const float* __restrict__ als,
                                                   const float* __restrict__ ald,
                                                   const int* __restrict__ off,
                                                   const int* __restrict__ esrc,
                                                   const float* __restrict__ b1,
                                                   unsigned short* __restrict__ out1,
                                                   float* __restrict__ bnsum8,
                                                   float* __restrict__ bnsumsq8) {
  __shared__ float bns[4][HC];
  __shared__ float bnq[4][HC];
  int wave = threadIdx.x >> 6;
  int node = blockIdx.x * 4 + wave;
  int lane = threadIdx.x & 63;
  int eg = lane >> 5;
  int c0 = (lane & 31) * 8;
  int hh = c0 >> 6;
  int beg = off[node], end = off[node + 1];
  float aldh = ald[node * NHEAD + hh];
  float a[8] = {0.f, 0.f, 0.f, 0.f, 0.f, 0.f, 0.f, 0.f};
  float zz = 0.f;
  int k = beg;
  for (; k + 16 <= end; k += 16) {
    int s[8];
    float w[8];
    uint2 u[8];
#pragma unroll
    for (int j = 0; j < 8; j++) s[j] = esrc[k + 2 * j + eg];
#pragma unroll
    for (int j = 0; j < 8; j++) {
      w[j] = __expf(lrelu(als[s[j] * NHEAD + hh] + aldh));
      u[j] = *(const uint2*)(h1f8 + s[j] * HC + c0);
    }
#pragma unroll
    for (int j = 0; j < 8; j++) {
      f32x2 p0 = __builtin_amdgcn_cvt_pk_f32_fp8(u[j].x, false);
      f32x2 p1 = __builtin_amdgcn_cvt_pk_f32_fp8(u[j].x, true);
      f32x2 p2 = __builtin_amdgcn_cvt_pk_f32_fp8(u[j].y, false);
      f32x2 p3 = __builtin_amdgcn_cvt_pk_f32_fp8(u[j].y, true);
      a[0] += w[j] * p0.x; a[1] += w[j] * p0.y;
      a[2] += w[j] * p1.x; a[3] += w[j] * p1.y;
      a[4] += w[j] * p2.x; a[5] += w[j] * p2.y;
      a[6] += w[j] * p3.x; a[7] += w[j] * p3.y;
      zz += w[j];
    }
  }
  if (k + 8 <= end) {  // 8-slot half-chunk
    int s[4];
    float w[4];
    uint2 u[4];
#pragma unroll
    for (int j = 0; j < 4; j++) s[j] = esrc[k + 2 * j + eg];
#pragma unroll
    for (int j = 0; j < 4; j++) {
      w[j] = __expf(lrelu(als[s[j] * NHEAD + hh] + aldh));
      u[j] = *(const uint2*)(h1f8 + s[j] * HC + c0);
    }
#pragma unroll
    for (int j = 0; j < 4; j++) {
      f32x2 p0 = __builtin_amdgcn_cvt_pk_f32_fp8(u[j].x, false);
      f32x2 p1 = __builtin_amdgcn_cvt_pk_f32_fp8(u[j].x, true);
      f32x2 p2 = __builtin_amdgcn_cvt_pk_f32_fp8(u[j].y, false);
      f32x2 p3 = __builtin_amdgcn_cvt_pk_f32_fp8(u[j].y, true);
      a[0] += w[j] * p0.x; a[1] += w[j] * p0.y;
      a[2] += w[j] * p1.x; a[3] += w[j] * p1.y;
      a[4] += w[j] * p2.x; a[5] += w[j] * p2.y;
      a[6] += w[j] * p3.x; a[7] += w[j] * p3.y;
      zz += w[j];
    }
    k += 8;
  }
  if (k < end) {  // 4-slot quarter-chunk
    int s[2];
    float w[2];
    uint2 u[2];
#pragma unroll
    for (int j = 0; j < 2; j++) s[j] = esrc[k + 2 * j + eg];
#pragma unroll
    for (int j = 0; j < 2; j++) {
      w[j] = __expf(lrelu(als[s[j] * NHEAD + hh] + aldh));
      u[j] = *(const uint2*)(h1f8 + s[j] * HC + c0);
    }
#pragma unroll
    for (int j = 0; j < 2; j++) {
      f32x2 p0 = __builtin_amdgcn_cvt_pk_f32_fp8(u[j].x, false);
      f32x2 p1 = __builtin_amdgcn_cvt_pk_f32_fp8(u[j].x, true);
      f32x2 p2 = __builtin_amdgcn_cvt_pk_f32_fp8(u[j].y, false);
      f32x2 p3 = __builtin_amdgcn_cvt_pk_f32_fp8(u[j].y, true);
      a[0] += w[j] * p0.x; a[1] += w[j] * p0.y;
      a[2] += w[j] * p1.x; a[3] += w[j] * p1.y;
      a[4] += w[j] * p2.x; a[5] += w[j] * p2.y;
      a[6] += w[j] * p3.x; a[7] += w[j] * p3.y;
      zz += w[j];
    }
  }
  // combine the two edge-groups (lanes L and L^32 cover the same channels)
#pragma unroll
  for (int j = 0; j < 8; j++) a[j] += __shfl_xor(a[j], 32, 64);
  zz += __shfl_xor(zz, 32, 64);
  if (eg == 0) {
    // self-loop from bf16 original
    float sw = __expf(lrelu(als[node * NHEAD + hh] + aldh));
    ushort4 vs0 = *(const ushort4*)(h1 + node * HC + c0);
    ushort4 vs1 = *(const ushort4*)(h1 + node * HC + c0 + 4);
    a[0] += sw * bf2f(vs0.x); a[1] += sw * bf2f(vs0.y);
    a[2] += sw * bf2f(vs0.z); a[3] += sw * bf2f(vs0.w);
    a[4] += sw * bf2f(vs1.x); a[5] += sw * bf2f(vs1.y);
    a[6] += sw * bf2f(vs1.z); a[7] += sw * bf2f(vs1.w);
    zz += sw;
    float inv = 1.f / zz;
    float4 bb0 = *(const float4*)(b1 + c0);
    float4 bb1 = *(const float4*)(b1 + c0 + 4);
    float ov[8];
    ov[0] = a[0] * inv + bb0.x; ov[1] = a[1] * inv + bb0.y;
    ov[2] = a[2] * inv + bb0.z; ov[3] = a[3] * inv + bb0.w;
    ov[4] = a[4] * inv + bb1.x; ov[5] = a[5] * inv + bb1.y;
    ov[6] = a[6] * inv + bb1.z; ov[7] = a[7] * inv + bb1.w;
    ushort4 o0, o1;
    o0.x = f2bf(ov[0]); o0.y = f2bf(ov[1]);
    o0.z = f2bf(ov[2]); o0.w = f2bf(ov[3]);
    o1.x = f2bf(ov[4]); o1.y = f2bf(ov[5]);
    o1.z = f2bf(ov[6]); o1.w = f2bf(ov[7]);
    *(ushort4*)(out1 + node * HC + c0) = o0;
    *(ushort4*)(out1 + node * HC + c0 + 4) = o1;
#pragma unroll
    for (int q = 0; q < 8; q++) {
      bns[wave][c0 + q] = ov[q];
      bnq[wave][c0 + q] = ov[q] * ov[q];
    }
  }
  __syncthreads();
  {
    int t = threadIdx.x;  // one channel per thread
    float s = bns[0][t] + bns[1][t] + bns[2][t] + bns[3][t];
    float q2 = bnq[0][t] + bnq[1][t] + bnq[2][t] + bnq[3][t];
    int sh = (blockIdx.x & 7) * HC;
    atomicAdd(&bnsum8[sh + t], s);
    atomicAdd(&bnsumsq8[sh + t], q2);
  }
}

// ---------------- GEMM2 + fused als2/ald2 + fp8 shadow: h2 = relu(bn(out1)) @ W2 -----
__global__ __launch_bounds__(256) void gemm2_kernel(const unsigned short* __restrict__ out1,
                                                    const unsigned short* __restrict__ W2p,
                                                    const float* __restrict__ bnsum8,
                                                    const float* __restrict__ bnsumsq8,
                                                    const float* __restrict__ gamma,
                                                    const float* __restrict__ beta,
                                                    const float* __restrict__ a_src2,
                                                    const float* __restrict__ a_dst2,
                                                    unsigned short* __restrict__ h2,
                                                    unsigned char* __restrict__ h2f8,
                                                    float* __restrict__ als2,
                                                    float* __restrict__ ald2) {
  __shared__ float scale_s[HC], shift_s[HC];
  __shared__ float sh_as[CDIM], sh_ad[CDIM];
  {
    int t = threadIdx.x;
    float su = 0.f, sq = 0.f;
#pragma unroll
    for (int j = 0; j < 8; j++) {
      su += bnsum8[j * HC + t];
      sq += bnsumsq8[j * HC + t];
    }
    float mu = su / (float)NN;
    float var = sq / (float)NN - mu * mu;
    float sc = gamma[t] * rsqrtf(var + 1e-5f);
    scale_s[t] = sc;
    shift_s[t] = beta[t] - mu * sc;
    if (t < CDIM) {
      sh_as[t] = a_src2[t];
      sh_ad[t] = a_dst2[t];
    }
  }
  __syncthreads();
  int wave = threadIdx.x >> 6, lane = threadIdx.x & 63;
  int tile = blockIdx.x * 4 + wave;
  if (tile >= NT1) return;
  int r0 = tile * 16, m = lane & 15, quad = lane >> 4;
  int row = r0 + m;
  short8 a[8];
#pragma unroll
  for (int kk = 0; kk < 8; kk++) {
    int kb = kk * 32 + quad * 8;
    short8 raw = *(const short8*)(out1 + row * HC + kb);
    alignas(16) unsigned short tmp[8];
#pragma unroll
    for (int j = 0; j < 8; j++) {
      tmp[j] = f2bf(relu(bf2f((unsigned short)raw[j]) * scale_s[kb + j] + shift_s[kb + j]));
    }
    a[kk] = *(const short8*)tmp;
  }
  float ps[4] = {0.f, 0.f, 0.f, 0.f};
  float pd[4] = {0.f, 0.f, 0.f, 0.f};
#pragma unroll
  for (int ng = 0; ng < 4; ng++) {
    f32x4 acc = {0.f, 0.f, 0.f, 0.f};
#pragma unroll
    for (int kk = 0; kk < 8; kk++) {
      short8 b = *(const short8*)(W2p + ((ng * 8 + kk) * 64 + lane) * 8);
      acc = __builtin_amdgcn_mfma_f32_16x16x32_bf16(a[kk], b, acc, 0, 0, 0);
    }
    int col = ng * 16 + m;
    float asv = sh_as[col], adv = sh_ad[col];
#pragma unroll
    for (int r = 0; r < 4; r++) {
      int rr = r0 + quad * 4 + r;
      h2[rr * CDIM + col] = f2bf(acc[r]);
      h2f8[rr * CDIM + col] = f2f8(acc[r]);
      ps[r] += acc[r] * asv;
      pd[r] += acc[r] * adv;
    }
  }
#pragma unroll
  for (int o = 1; o < 16; o <<= 1) {
#pragma unroll
    for (int r = 0; r < 4; r++) {
      ps[r] += __shfl_xor(ps[r], o, 64);
      pd[r] += __shfl_xor(pd[r], o, 64);
    }
  }
  if (m == 0) {
#pragma unroll
    for (int r = 0; r < 4; r++) {
      int rr = r0 + quad * 4 + r;
      als2[rr] = ps[r];
      ald2[rr] = pd[r];
    }
  }
}

// ---------------- GAT layer2 agg + ReLU + pooling ----------------
// 4 edge-groups x 16 lanes x 4 fp8 channels (uint gathers into the 3.2MB L2-resident
// h2f8 table; bf16 self-loop keeps precision). 4-padded CSR: 16-slot main chunks +
// optional 8-slot half-chunk + optional 4-slot quarter-chunk. Pooled atomics
// block-combined in LDS.
__global__ __launch_bounds__(256) void agg2_kernel(const unsigned short* __restrict__ h2,
                                                   const unsigned char* __restrict__ h2f8,
                                                   const float* __restrict__ als2,
                                                   const float* __restrict__ ald2,
                                                   const int* __restrict__ off,
                                                   const int* __restrict__ esrc,
                                                   const float* __restrict__ b2,
                                                   const int* __restrict__ batch,
                                                   float* __restrict__ pooled) {
  __shared__ float svv[4][CDIM];
  __shared__ int sg[4];
  int wave = threadIdx.x >> 6;
  int node = blockIdx.x * 4 + wave;
  int lane = threadIdx.x & 63;
  int eg = lane >> 4;          // 4 edge groups
  int cp = (lane & 15) * 4;    // 4 channels per lane
  int beg = off[node], end = off[node + 1];
  float aldn = ald2[node];
  float a0 = 0.f, a1 = 0.f, a2 = 0.f, a3 = 0.f, zz = 0.f;
  int k = beg;
  for (; k + 16 <= end; k += 16) {
    int s[4];
    float w[4];
    unsigned int u[4];
#pragma unroll
    for (int j = 0; j < 4; j++) s[j] = esrc[k + 4 * j + eg];
#pragma unroll
    for (int j = 0; j < 4; j++) {
      w[j] = __expf(lrelu(als2[s[j]] + aldn));
      u[j] = *(const unsigned int*)(h2f8 + s[j] * CDIM + cp);
    }
#pragma unroll
    for (int j = 0; j < 4; j++) {
      f32x2 p0 = __builtin_amdgcn_cvt_pk_f32_fp8(u[j], false);
      f32x2 p1 = __builtin_amdgcn_cvt_pk_f32_fp8(u[j], true);
      a0 += w[j] * p0.x;
      a1 += w[j] * p0.y;
      a2 += w[j] * p1.x;
      a3 += w[j] * p1.y;
      zz += w[j];
    }
  }
  if (k + 8 <= end) {  // 8-slot half-chunk
    int s[2];
    float w[2];
    unsigned int u[2];
#pragma unroll
    for (int j = 0; j < 2; j++) s[j] = esrc[k + 4 * j + eg];
#pragma unroll
    for (int j = 0; j < 2; j++) {
      w[j] = __expf(lrelu(als2[s[j]] + aldn));
      u[j] = *(const unsigned int*)(h2f8 + s[j] * CDIM + cp);
    }
#pragma unroll
    for (int j = 0; j < 2; j++) {
      f32x2 p0 = __builtin_amdgcn_cvt_pk_f32_fp8(u[j], false);
      f32x2 p1 = __builtin_amdgcn_cvt_pk_f32_fp8(u[j], true);
      a0 += w[j] * p0.x;
      a1 += w[j] * p0.y;
      a2 += w[j] * p1.x;
      a3 += w[j] * p1.y;
      zz += w[j];
    }
    k += 8;
  }
  if (k < end) {  // 4-slot quarter-chunk
    int s0 = esrc[k + eg];
    float w0 = __expf(lrelu(als2[s0] + aldn));
    unsigned int u0 = *(const unsigned int*)(h2f8 + s0 * CDIM + cp);
    f32x2 p0 = __builtin_amdgcn_cvt_pk_f32_fp8(u0, false);
    f32x2 p1 = __builtin_amdgcn_cvt_pk_f32_fp8(u0, true);
    a0 += w0 * p0.x;
    a1 += w0 * p0.y;
    a2 += w0 * p1.x;
    a3 += w0 * p1.y;
    zz += w0;
  }
  // combine the four edge-groups (lanes sharing (lane&15) cover same channels)
  a0 += __shfl_xor(a0, 16, 64); a0 += __shfl_xor(a0, 32, 64);
  a1 += __shfl_xor(a1, 16, 64); a1 += __shfl_xor(a1, 32, 64);
  a2 += __shfl_xor(a2, 16, 64); a2 += __shfl_xor(a2, 32, 64);
  a3 += __shfl_xor(a3, 16, 64); a3 += __shfl_xor(a3, 32, 64);
  zz += __shfl_xor(zz, 16, 64); zz += __shfl_xor(zz, 32, 64);
  if (eg == 0) {
    float sw = __expf(lrelu(als2[node] + aldn));
    ushort4 vs = *(const ushort4*)(h2 + node * CDIM + cp);
    a0 += sw * bf2f(vs.x);
    a1 += sw * bf2f(vs.y);
    a2 += sw * bf2f(vs.z);
    a3 += sw * bf2f(vs.w);
    zz += sw;
    float inv = 1.f / zz;
    float4 bb = *(const float4*)(b2 + cp);
    svv[wave][cp + 0] = relu(a0 * inv + bb.x);
    svv[wave][cp + 1] = relu(a1 * inv + bb.y);
    svv[wave][cp + 2] = relu(a2 * inv + bb.z);
    svv[wave][cp + 3] = relu(a3 * inv + bb.w);
    if (lane == 0) sg[wave] = batch[node];
  }
  __syncthreads();
  int t = threadIdx.x;
  if (t < CDIM) {
    int g0 = sg[0], g1 = sg[1], g2 = sg[2], g3 = sg[3];
#pragma unroll
    for (int w = 0; w < 4; w++) {
      int gs[4] = {g0, g1, g2, g3};
      int gw = gs[w];
      bool first = true;
#pragma unroll
      for (int w2 = 0; w2 < 4; w2++)
        if (w2 < w && gs[w2] == gw) first = false;
      if (first) {
        float acc = svv[w][t];
#pragma unroll
        for (int w2 = 0; w2 < 4; w2++)
          if (w2 > w && gs[w2] == gw) acc += svv[w2][t];
        atomicAdd(&pooled[gw * CDIM + t], acc);
      }
    }
  }
}

// ---------------- pooled mean + classifier (f32 output); counts via binary search ----
__global__ void cls_kernel(const float* __restrict__ pooled, const int* __restrict__ batch,
                           const float* __restrict__ cW1, const float* __restrict__ cb1,
                           const float* __restrict__ cW2, const float* __restrict__ cb2,
                           float* __restrict__ out) {
  __shared__ float p[64];
  __shared__ float z[32];
  int g = blockIdx.x, t = threadIdx.x;
  int lo = 0, hi = NN;
  while (lo < hi) { int mid = (lo + hi) >> 1; if (batch[mid] < g) lo = mid + 1; else hi = mid; }
  int start = lo;
  lo = 0; hi = NN;
  while (lo < hi) { int mid = (lo + hi) >> 1; if (batch[mid] <= g) lo = mid + 1; else hi = mid; }
  int c = lo - start;
  float cnt = (float)(c > 0 ? c : 1);
  p[t] = pooled[g * CDIM + t] / cnt;
  __syncthreads();
  if (t < 32) {
    float a = cb1[t];
    for (int k = 0; k < 64; k++) a += p[k] * cW1[k * 32 + t];
    z[t] = relu(a);
  }
  __syncthreads();
  if (t < NCLS) {
    float a = cb2[t];
    for (int k = 0; k < 32; k++) a += z[k] * cW2[k * NCLS + t];
    out[g * NCLS + t] = a;
  }
}

extern "C" void kernel_launch(void* const* d_in, const int* in_sizes, int n_in,
                              void* d_out, int out_size, void* d_ws, size_t ws_size,
                              hipStream_t stream) {
  const float* x = (const float*)d_in[0];
  const int* edge_index = (const int*)d_in[1];
  const int* batch = (const int*)d_in[2];
  const float* W1 = (const float*)d_in[3];
  const float* a_src1 = (const float*)d_in[4];
  const float* a_dst1 = (const float*)d_in[5];
  const float* b1 = (const float*)d_in[6];
  const float* gamma = (const float*)d_in[7];
  const float* beta = (const float*)d_in[8];
  const float* W2 = (const float*)d_in[9];
  const float* a_src2 = (const float*)d_in[10];
  const float* a_dst2 = (const float*)d_in[11];
  const float* b2 = (const float*)d_in[12];
  const float* cW1 = (const float*)d_in[13];
  const float* cb1 = (const float*)d_in[14];
  const float* cW2 = (const float*)d_in[15];
  const float* cb2 = (const float*)d_in[16];

  // ---- workspace layout ----
  // zero region (contiguous, zeroed every call): deg8 | bnsum8 | bnsumsq8 | pooled
  int* deg8 = (int*)d_ws;
  float* bnsum8 = (float*)(deg8 + 8 * NN);
  float* bnsumsq8 = bnsum8 + 8 * HC;
  float* pooled = bnsumsq8 + 8 * HC;
  char* p = (char*)(pooled + NGRAPH * CDIM);
  auto align256 = [&](char*& q) {
    size_t a = (size_t)(q - (char*)d_ws);
    a = (a + 255) & ~(size_t)255;
    q = (char*)d_ws + a;
  };
  align256(p);
  int* degsum = (int*)p;          p += (size_t)NN * 4;       align256(p);
  int* offs = (int*)p;            p += (size_t)(NN + 1) * 4; align256(p);
  int* cursor8 = (int*)p;         p += (size_t)8 * NN * 4;   align256(p);
  int* esrc = (int*)p;            p += (size_t)(NE + 16 * NN) * 4; align256(p);
  int* bsum = (int*)p;            p += 256 * 4;              align256(p);
  unsigned short* h1 = (unsigned short*)p;   p += (size_t)NN * HC * 2;          align256(p);
  unsigned short* out1 = (unsigned short*)p; p += (size_t)NN * HC * 2;          align256(p);
  unsigned short* h2 = (unsigned short*)p;   p += (size_t)(NN + 1) * CDIM * 2;  align256(p);
  float* als1 = (float*)p;        p += (size_t)(NN + 1) * NHEAD * 4; align256(p);
  float* ald1 = (float*)p;        p += (size_t)NN * NHEAD * 4;       align256(p);
  float* als2v = (float*)p;       p += (size_t)(NN + 1) * 4;         align256(p);
  float* ald2v = (float*)p;       p += (size_t)NN * 4;               align256(p);
  unsigned char* h1f8 = (unsigned char*)p; p += (size_t)(NN + 1) * HC;  align256(p);
  unsigned char* h2f8 = (unsigned char*)p; p += (size_t)(NN + 1) * CDIM; align256(p);
  unsigned short* W1p = (unsigned short*)p; p += 32768 * 2;    align256(p);
  unsigned short* W2p = (unsigned short*)p; p += 16384 * 2;    align256(p);

  repack_kernel<<<(ZWORDS + 255) / 256, 256, 0, stream>>>(W1, W2, W1p, W2p, als1, als2v,
                                                          h1f8, h2, h2f8, (int*)d_ws);
  hist_kernel<<<(NE + 255) / 256, 256, 0, stream>>>(edge_index, deg8);
  scan_a<<<NB, 256, 0, stream>>>(deg8, bsum, degsum);
  scan_c<<<NB, 256, 0, stream>>>(degsum, deg8, bsum, offs, cursor8, esrc);
  scatgemm1_kernel<<<2048 + (NT1 + 3) / 4, 256, 0, stream>>>(
      edge_index, cursor8, esrc, x, W1p, a_src1, a_dst1, h1, h1f8, als1, ald1);
  agg1_kernel<<<NN / 4, 256, 0, stream>>>(h1, h1f8, als1, ald1, offs, esrc, b1, out1,
                                          bnsum8, bnsumsq8);
  gemm2_kernel<<<(NT1 + 3) / 4, 256, 0, stream>>>(out1, W2p, bnsum8, bnsumsq8, gamma, beta,
                                                  a_src2, a_dst2, h2, h2f8, als2v, ald2v);
  agg2_kernel<<<NN / 4, 256, 0, stream>>>(h2, h2f8, als2v, ald2v, offs, esrc, b2,
                                          batch, pooled);
  cls_kernel<<<NGRAPH, 64, 0, stream>>>(pooled, batch, cW1, cb1, cW2, cb2, (float*)d_out);
}

// Round 12
// 286.233 us; speedup vs baseline: 1.1223x; 1.0028x over previous
//
#include <hip/hip_runtime.h>
#include <hip/hip_bf16.h>
#include <hip/hip_fp8.h>

#define NN 50000
#define NE 800000
#define DIN 128
#define HC 256
#define NHEAD 4
#define CDIM 64
#define NGRAPH 512
#define NCLS 10
#define NEG_SLOPE 0.2f
#define NB 196   // ceil(NN/256)
#define NT1 3125 // NN/16 M-tiles
#define HB 3125  // hist blocks = ceil(NE/256)
// zero region words: deg8 | bnsum8(8*HC) | bnsumsq8(8*HC) | pooled
#define ZWORDS (8 * NN + 8 * HC + 8 * HC + NGRAPH * CDIM)

typedef __hip_bfloat16 bf16;
typedef __attribute__((ext_vector_type(8))) short short8;
typedef __attribute__((ext_vector_type(4))) float f32x4;
typedef __attribute__((ext_vector_type(2))) float f32x2;

__device__ __forceinline__ float bf2f(unsigned short u) {
  union { unsigned int i; float f; } x;
  x.i = ((unsigned int)u) << 16;
  return x.f;
}
__device__ __forceinline__ unsigned short f2bf(float f) {
  bf16 v = __float2bfloat16(f);
  union { bf16 b; unsigned short s; } x;
  x.b = v;
  return x.s;
}
// fp8 e4m3 (OCP) encode/decode via HIP type
__device__ __forceinline__ unsigned char f2f8(float f) {
  __hip_fp8_e4m3 q(f);
  return (unsigned char)q.__x;
}
__device__ __forceinline__ float lrelu(float x) { return x >= 0.f ? x : NEG_SLOPE * x; }
// NaN-propagating relu (fmaxf would silently clamp NaN to 0)
__device__ __forceinline__ float relu(float x) { return x < 0.f ? 0.f : x; }

// ---------------- FUSED zero + repack + sentinel init ----------------
__global__ void repack_kernel(const float* __restrict__ W1, const float* __restrict__ W2,
                              unsigned short* __restrict__ W1p, unsigned short* __restrict__ W2p,
                              float* __restrict__ als1, float* __restrict__ als2v,
                              unsigned char* __restrict__ h1f8, unsigned short* __restrict__ h2,
                              unsigned char* __restrict__ h2f8, int* __restrict__ zp) {
  int i = blockIdx.x * 256 + threadIdx.x;
  if (i < ZWORDS) zp[i] = 0;
  if (blockIdx.x == 0) {
    int t = threadIdx.x;
    if (t < NHEAD) als1[NN * NHEAD + t] = -1e30f;
    if (t == NHEAD) als2v[NN] = -1e30f;
    if (t < 64) ((unsigned int*)(h1f8 + (size_t)NN * HC))[t] = 0u;
    if (t < 32) ((unsigned int*)(h2 + (size_t)NN * CDIM))[t] = 0u;
    if (t < 16) ((unsigned int*)(h2f8 + (size_t)NN * CDIM))[t] = 0u;
  }
  if (i < 16 * 4 * 64 * 8) {  // W1: [128,256] -> ng(16) kk(4) lane(64) j(8)
    int j = i & 7, lane = (i >> 3) & 63, kk = (i >> 9) & 3, ng = i >> 11;
    int n = ng * 16 + (lane & 15);
    int k = kk * 32 + (lane >> 4) * 8 + j;
    W1p[i] = f2bf(W1[k * HC + n]);
  }
  int i2 = i - 16 * 4 * 64 * 8;
  if (i2 >= 0 && i2 < 4 * 8 * 64 * 8) {  // W2: [256,64] -> ng(4) kk(8) lane(64) j(8)
    int j = i2 & 7, lane = (i2 >> 3) & 63, kk = (i2 >> 9) & 7, ng = i2 >> 12;
    int n = ng * 16 + (lane & 15);
    int k = kk * 32 + (lane >> 4) * 8 + j;
    W2p[i2] = f2bf(W2[k * CDIM + n]);
  }
}

// ---------------- FUSED: edge histogram (blocks 0..HB-1) + GEMM1 (rest) -------------
// Re-paired fusion (r12): hist's atomicAdd is fire-and-forget (no return value; HW
// coalesces per-wave) so it tolerates the VGPR-64 envelope and hides under gemm1's
// MFMA. Scatter (whose atomic RETURNS the cursor, latency-serialized) now runs as a
// separate lean kernel at full occupancy. GEMM1 emits the fp8 shadow + fused als/ald.
__global__ __launch_bounds__(256) void histgemm1_kernel(
    const int* __restrict__ ei, int* __restrict__ deg8,
    const float* __restrict__ x, const unsigned short* __restrict__ W1p,
    const float* __restrict__ a_src, const float* __restrict__ a_dst,
    unsigned short* __restrict__ h1, unsigned char* __restrict__ h1f8,
    float* __restrict__ als, float* __restrict__ ald) {
  __shared__ float sh_as[HC], sh_ad[HC];
  if (blockIdx.x < HB) {
    int i = blockIdx.x * 256 + threadIdx.x;
    if (i < NE) atomicAdd(&deg8[(i & 7) * NN + ei[NE + i]], 1);
    return;
  }
  {
    int t = threadIdx.x;
    sh_as[t] = a_src[t];
    sh_ad[t] = a_dst[t];
  }
  __syncthreads();
  int wave = threadIdx.x >> 6, lane = threadIdx.x & 63;
  int tile = (blockIdx.x - HB) * 4 + wave;
  if (tile >= NT1) return;
  int r0 = tile * 16, m = lane & 15, quad = lane >> 4;
  int row = r0 + m;
  short8 a[4];
#pragma unroll
  for (int kk = 0; kk < 4; kk++) {
    int kb = kk * 32 + quad * 8;
    float4 f0 = *(const float4*)(x + row * DIN + kb);
    float4 f1 = *(const float4*)(x + row * DIN + kb + 4);
    alignas(16) unsigned short tmp[8];
    tmp[0] = f2bf(f0.x); tmp[1] = f2bf(f0.y); tmp[2] = f2bf(f0.z); tmp[3] = f2bf(f0.w);
    tmp[4] = f2bf(f1.x); tmp[5] = f2bf(f1.y); tmp[6] = f2bf(f1.z); tmp[7] = f2bf(f1.w);
    a[kk] = *(const short8*)tmp;
  }
#pragma unroll
  for (int hg = 0; hg < 4; hg++) {
    float ps[4] = {0.f, 0.f, 0.f, 0.f};
    float pd[4] = {0.f, 0.f, 0.f, 0.f};
#pragma unroll
    for (int sub = 0; sub < 4; sub++) {
      int ng = hg * 4 + sub;
      f32x4 acc = {0.f, 0.f, 0.f, 0.f};
#pragma unroll
      for (int kk = 0; kk < 4; kk++) {
        short8 b = *(const short8*)(W1p + ((ng * 4 + kk) * 64 + lane) * 8);
        acc = __builtin_amdgcn_mfma_f32_16x16x32_bf16(a[kk], b, acc, 0, 0, 0);
      }
      int col = ng * 16 + m;
      float asv = sh_as[col], adv = sh_ad[col];
#pragma unroll
      for (int r = 0; r < 4; r++) {
        int rr = r0 + quad * 4 + r;
        h1[rr * HC + col] = f2bf(acc[r]);
        h1f8[rr * HC + col] = f2f8(acc[r]);
        ps[r] += acc[r] * asv;
        pd[r] += acc[r] * adv;
      }
    }
#pragma unroll
    for (int o = 1; o < 16; o <<= 1) {
#pragma unroll
      for (int r = 0; r < 4; r++) {
        ps[r] += __shfl_xor(ps[r], o, 64);
        pd[r] += __shfl_xor(pd[r], o, 64);
      }
    }
    if (m == 0) {
#pragma unroll
      for (int r = 0; r < 4; r++) {
        int rr = r0 + quad * 4 + r;
        als[rr * NHEAD + hg] = ps[r];
        ald[rr * NHEAD + hg] = pd[r];
      }
    }
  }
}

// ---------------- exclusive scan of 4-PADDED deg -> off, sharded cursors -------------
__global__ void scan_a(const int* __restrict__ deg8, int* __restrict__ bsum,
                       int* __restrict__ degsum) {
  __shared__ int sm[256];
  int t = threadIdx.x, i = blockIdx.x * 256 + t;
  int d = 0;
  if (i < NN) {
#pragma unroll
    for (int j = 0; j < 8; j++) d += deg8[j * NN + i];
  }
  int dp = (d + 3) & ~3;
  if (i < NN) degsum[i] = dp;
  sm[t] = dp;
  __syncthreads();
  for (int s = 128; s > 0; s >>= 1) {
    if (t < s) sm[t] += sm[t + s];
    __syncthreads();
  }
  if (t == 0) bsum[blockIdx.x] = sm[0];
}
// scan_c also performs scan_b's job (every block redundantly scans the 196 block
// sums in LDS) -- saves a kernel launch + dependency bubble.
__global__ void scan_c(const int* __restrict__ degsum, const int* __restrict__ deg8,
                       const int* __restrict__ bsum,
                       int* __restrict__ off, int* __restrict__ cursor8,
                       int* __restrict__ esrc) {
  __shared__ int sm[256];
  __shared__ int pre[256];
  int t = threadIdx.x, i = blockIdx.x * 256 + t;
  int own = (t < NB) ? bsum[t] : 0;
  sm[t] = own;
  pre[t] = own;
  __syncthreads();
  for (int s = 1; s < 256; s <<= 1) {
    int v = (t >= s) ? sm[t - s] : 0;
    __syncthreads();
    sm[t] += v;
    __syncthreads();
  }
  int bbase = sm[blockIdx.x] - pre[blockIdx.x];  // exclusive prefix of block sums
  __syncthreads();
  int dp = (i < NN) ? degsum[i] : 0;
  sm[t] = dp;
  __syncthreads();
  for (int s = 1; s < 256; s <<= 1) {
    int v = (t >= s) ? sm[t - s] : 0;
    __syncthreads();
    sm[t] += v;
    __syncthreads();
  }
  int excl = bbase + sm[t] - dp;
  if (i < NN) {
    off[i] = excl;
    int base = excl;
#pragma unroll
    for (int j = 0; j < 8; j++) {
      cursor8[j * NN + i] = base;
      base += deg8[j * NN + i];
    }
    // fill pad slots (at most 3) with the sentinel src (weight == 0, zero payload)
    for (int q = base; q < excl + dp; q++) esrc[q] = NN;
    if (i == NN - 1) off[NN] = excl + dp;
  }
}

// ---------------- XCD-affine scatter: block (chunk c, xcd x) scatters only ----------
// Lean separate kernel (VGPR ~28, full occupancy): the cursor atomicAdd RETURNS a
// value, so each matching edge is a latency round-trip -- needs max wave count.
__global__ void scatter_kernel(const int* __restrict__ ei, int* __restrict__ cursor8,
                               int* __restrict__ esrc) {
  int xcd = blockIdx.x & 7;
  int chunk = blockIdx.x >> 3;
  int lo = chunk * (NE / 256);
  int hi = lo + (NE / 256);
  for (int e = lo + threadIdx.x; e < hi; e += 256) {
    int d = ei[NE + e];
    if (d / (NN / 8) == xcd) {
      int s = ei[e];
      int p = atomicAdd(&cursor8[(e & 7) * NN + d], 1);
      esrc[p] = s;
    }
  }
}

// ---------------- GAT layer1 aggregation + FUSED BN stats ----------------
__global__ __launch_bounds__(256) void agg1_kernel(const unsigned short* __restrict__ h1,
                                                   const unsigned char* __restrict__ h1f8,
                                                   const float* __restrict__ als,
                                                   const float* __restrict__ ald,
                                                   const int* __restrict__ off,
                                                   const int* __restrict__ esrc,
                                                   const float* __restrict__ b1,
                                                   unsigned short* __restrict__ out1,
                                                   float* __restrict__ bnsum8,
                                                   float* __restrict__ bnsumsq8) {
  __shared__ float bns[4][HC];
  __shared__ float bnq[4][HC];
  int wave = threadIdx.x >> 6;
  int node = blockIdx.x * 4 + wave;
  int lane = threadIdx.x & 63;
  int eg = lane >> 5;
  int c0 = (lane & 31) * 8;
  int hh = c0 >> 6;
  int beg = off[node], end = off[node + 1];
  float aldh = ald[node * NHEAD + hh];
  float a[8] = {0.f, 0.f, 0.f, 0.f, 0.f, 0.f, 0.f, 0.f};
  float zz = 0.f;
  int k = beg;
  for (; k + 16 <= end; k += 16) {
    int s[8];
    float w[8];
    uint2 u[8];
#pragma unroll
    for (int j = 0; j < 8; j++) s[j] = esrc[k + 2 * j + eg];
#pragma unroll
    for (int j = 0; j < 8; j++) {
      w[j] = __expf(lrelu(als[s[j] * NHEAD + hh] + aldh));
      u[j] = *(const uint2*)(h1f8 + s[j] * HC + c0);
    }
#pragma unroll
    for (int j = 0; j < 8; j++) {
      f32x2 p0 = __builtin_amdgcn_cvt_pk_f32_fp8(u[j].x, false);
      f32x2 p1 = __builtin_amdgcn_cvt_pk_f32_fp8(u[j].x, true);
      f32x2 p2 = __builtin_amdgcn_cvt_pk_f32_fp8(u[j].y, false);
      f32x2 p3 = __builtin_amdgcn_cvt_pk_f32_fp8(u[j].y, true);
      a[0] += w[j] * p0.x; a[1] += w[j] * p0.y;
      a[2] += w[j] * p1.x; a[3] += w[j] * p1.y;
      a[4] += w[j] * p2.x; a[5] += w[j] * p2.y;
      a[6] += w[j] * p3.x; a[7] += w[j] * p3.y;
      zz += w[j];
    }
  }
  if (k + 8 <= end) {  // 8-slot half-chunk
    int s[4];
    float w[4];
    uint2 u[4];
#pragma unroll
    for (int j = 0; j < 4; j++) s[j] = esrc[k + 2 * j + eg];
#pragma unroll
    for (int j = 0; j < 4; j++) {
      w[j] = __expf(lrelu(als[s[j] * NHEAD + hh] + aldh));
      u[j] = *(const uint2*)(h1f8 + s[j] * HC + c0);
    }
#pragma unroll
    for (int j = 0; j < 4; j++) {
      f32x2 p0 = __builtin_amdgcn_cvt_pk_f32_fp8(u[j].x, false);
      f32x2 p1 = __builtin_amdgcn_cvt_pk_f32_fp8(u[j].x, true);
      f32x2 p2 = __builtin_amdgcn_cvt_pk_f32_fp8(u[j].y, false);
      f32x2 p3 = __builtin_amdgcn_cvt_pk_f32_fp8(u[j].y, true);
      a[0] += w[j] * p0.x; a[1] += w[j] * p0.y;
      a[2] += w[j] * p1.x; a[3] += w[j] * p1.y;
      a[4] += w[j] * p2.x; a[5] += w[j] * p2.y;
      a[6] += w[j] * p3.x; a[7] += w[j] * p3.y;
      zz += w[j];
    }
    k += 8;
  }
  if (k < end) {  // 4-slot quarter-chunk
    int s[2];
    float w[2];
    uint2 u[2];
#pragma unroll
    for (int j = 0; j < 2; j++) s[j] = esrc[k + 2 * j + eg];
#pragma unroll
    for (int j = 0; j < 2; j++) {
      w[j] = __expf(lrelu(als[s[j] * NHEAD + hh] + aldh));
      u[j] = *(const uint2*)(h1f8 + s[j] * HC + c0);
    }
#pragma unroll
    for (int j = 0; j < 2; j++) {
      f32x2 p0 = __builtin_amdgcn_cvt_pk_f32_fp8(u[j].x, false);
      f32x2 p1 = __builtin_amdgcn_cvt_pk_f32_fp8(u[j].x, true);
      f32x2 p2 = __builtin_amdgcn_cvt_pk_f32_fp8(u[j].y, false);
      f32x2 p3 = __builtin_amdgcn_cvt_pk_f32_fp8(u[j].y, true);
      a[0] += w[j] * p0.x; a[1] += w[j] * p0.y;
      a[2] += w[j] * p1.x; a[3] += w[j] * p1.y;
      a[4] += w[j] * p2.x; a[5] += w[j] * p2.y;
      a[6] += w[j] * p3.x; a[7] += w[j] * p3.y;
      zz += w[j];
    }
  }
  // combine the two edge-groups (lanes L and L^32 cover the same channels)
#pragma unroll
  for (int j = 0; j < 8; j++) a[j] += __shfl_xor(a[j], 32, 64);
  zz += __shfl_xor(zz, 32, 64);
  if (eg == 0) {
    // self-loop from bf16 original
    float sw = __expf(lrelu(als[node * NHEAD + hh] + aldh));
    ushort4 vs0 = *(const ushort4*)(h1 + node * HC + c0);
    ushort4 vs1 = *(const ushort4*)(h1 + node * HC + c0 + 4);
    a[0] += sw * bf2f(vs0.x); a[1] += sw * bf2f(vs0.y);
    a[2] += sw * bf2f(vs0.z); a[3] += sw * bf2f(vs0.w);
    a[4] += sw * bf2f(vs1.x); a[5] += sw * bf2f(vs1.y);
    a[6] += sw * bf2f(vs1.z); a[7] += sw * bf2f(vs1.w);
    zz += sw;
    float inv = 1.f / zz;
    float4 bb0 = *(const float4*)(b1 + c0);
    float4 bb1 = *(const float4*)(b1 + c0 + 4);
    float ov[8];
    ov[0] = a[0] * inv + bb0.x; ov[1] = a[1] * inv + bb0.y;
    ov[2] = a[2] * inv + bb0.z; ov[3] = a[3] * inv + bb0.w;
    ov[4] = a[4] * inv + bb1.x; ov[5] = a[5] * inv + bb1.y;
    ov[6] = a[6] * inv + bb1.z; ov[7] = a[7] * inv + bb1.w;
    ushort4 o0, o1;
    o0.x = f2bf(ov[0]); o0.y = f2bf(ov[1]);
    o0.z = f2bf(ov[2]); o0.w = f2bf(ov[3]);
    o1.x = f2bf(ov[4]); o1.y = f2bf(ov[5]);
    o1.z = f2bf(ov[6]); o1.w = f2bf(ov[7]);
    *(ushort4*)(out1 + node * HC + c0) = o0;
    *(ushort4*)(out1 + node * HC + c0 + 4) = o1;
#pragma unroll
    for (int q = 0; q < 8; q++) {
      bns[wave][c0 + q] = ov[q];
      bnq[wave][c0 + q] = ov[q] * ov[q];
    }
  }
  __syncthreads();
  {
    int t = threadIdx.x;  // one channel per thread
    float s = bns[0][t] + bns[1][t] + bns[2][t] + bns[3][t];
    float q2 = bnq[0][t] + bnq[1][t] + bnq[2][t] + bnq[3][t];
    int sh = (blockIdx.x & 7) * HC;
    atomicAdd(&bnsum8[sh + t], s);
    atomicAdd(&bnsumsq8[sh + t], q2);
  }
}

// ---------------- GEMM2 + fused als2/ald2 + fp8 shadow: h2 = relu(bn(out1)) @ W2 -----
__global__ __launch_bounds__(256) void gemm2_kernel(const unsigned short* __restrict__ out1,
                                                    const unsigned short* __restrict__ W2p,
                                                    const float* __restrict__ bnsum8,
                                                    const float* __restrict__ bnsumsq8,
                                                    const float* __restrict__ gamma,
                                                    const float* __restrict__ beta,
                                                    const float* __restrict__ a_src2,
                                                    const float* __restrict__ a_dst2,
                                                    unsigned short* __restrict__ h2,
                                                    unsigned char* __restrict__ h2f8,
                                                    float* __restrict__ als2,
                                                    float* __restrict__ ald2) {
  __shared__ float scale_s[HC], shift_s[HC];
  __shared__ float sh_as[CDIM], sh_ad[CDIM];
  {
    int t = threadIdx.x;
    float su = 0.f, sq = 0.f;
#pragma unroll
    for (int j = 0; j < 8; j++) {
      su += bnsum8[j * HC + t];
      sq += bnsumsq8[j * HC + t];
    }
    float mu = su / (float)NN;
    float var = sq / (float)NN - mu * mu;
    float sc = gamma[t] * rsqrtf(var + 1e-5f);
    scale_s[t] = sc;
    shift_s[t] = beta[t] - mu * sc;
    if (t < CDIM) {
      sh_as[t] = a_src2[t];
      sh_ad[t] = a_dst2[t];
    }
  }
  __syncthreads();
  int wave = threadIdx.x >> 6, lane = threadIdx.x & 63;
  int tile = blockIdx.x * 4 + wave;
  if (tile >= NT1) return;
  int r0 = tile * 16, m = lane & 15, quad = lane >> 4;
  int row = r0 + m;
  short8 a[8];
#pragma unroll
  for (int kk = 0; kk < 8; kk++) {
    int kb = kk * 32 + quad * 8;
    short8 raw = *(const short8*)(out1 + row * HC + kb);
    alignas(16) unsigned short tmp[8];
#pragma unroll
    for (int j = 0; j < 8; j++) {
      tmp[j] = f2bf(relu(bf2f((unsigned short)raw[j]) * scale_s[kb + j] + shift_s[kb + j]));
    }
    a[kk] = *(const short8*)tmp;
  }
  float ps[4] = {0.f, 0.f, 0.f, 0.f};
  float pd[4] = {0.f, 0.f, 0.f, 0.f};
#pragma unroll
  for (int ng = 0; ng < 4; ng++) {
    f32x4 acc = {0.f, 0.f, 0.f, 0.f};
#pragma unroll
    for (int kk = 0; kk < 8; kk++) {
      short8 b = *(const short8*)(W2p + ((ng * 8 + kk) * 64 + lane) * 8);
      acc = __builtin_amdgcn_mfma_f32_16x16x32_bf16(a[kk], b, acc, 0, 0, 0);
    }
    int col = ng * 16 + m;
    float asv = sh_as[col], adv = sh_ad[col];
#pragma unroll
    for (int r = 0; r < 4; r++) {
      int rr = r0 + quad * 4 + r;
      h2[rr * CDIM + col] = f2bf(acc[r]);
      h2f8[rr * CDIM + col] = f2f8(acc[r]);
      ps[r] += acc[r] * asv;
      pd[r] += acc[r] * adv;
    }
  }
#pragma unroll
  for (int o = 1; o < 16; o <<= 1) {
#pragma unroll
    for (int r = 0; r < 4; r++) {
      ps[r] += __shfl_xor(ps[r], o, 64);
      pd[r] += __shfl_xor(pd[r], o, 64);
    }
  }
  if (m == 0) {
#pragma unroll
    for (int r = 0; r < 4; r++) {
      int rr = r0 + quad * 4 + r;
      als2[rr] = ps[r];
      ald2[rr] = pd[r];
    }
  }
}

// ---------------- GAT layer2 agg + ReLU + pooling ----------------
__global__ __launch_bounds__(256) void agg2_kernel(const unsigned short* __restrict__ h2,
                                                   const unsigned char* __restrict__ h2f8,
                                                   const float* __restrict__ als2,
                                                   const float* __restrict__ ald2,
                                                   const int* __restrict__ off,
                                                   const int* __restrict__ esrc,
                                                   const float* __restrict__ b2,
                                                   const int* __restrict__ batch,
                                                   float* __restrict__ pooled) {
  __shared__ float svv[4][CDIM];
  __shared__ int sg[4];
  int wave = threadIdx.x >> 6;
  int node = blockIdx.x * 4 + wave;
  int lane = threadIdx.x & 63;
  int eg = lane >> 4;          // 4 edge groups
  int cp = (lane & 15) * 4;    // 4 channels per lane
  int beg = off[node], end = off[node + 1];
  float aldn = ald2[node];
  float a0 = 0.f, a1 = 0.f, a2 = 0.f, a3 = 0.f, zz = 0.f;
  int k = beg;
  for (; k + 16 <= end; k += 16) {
    int s[4];
    float w[4];
    unsigned int u[4];
#pragma unroll
    for (int j = 0; j < 4; j++) s[j] = esrc[k + 4 * j + eg];
#pragma unroll
    for (int j = 0; j < 4; j++) {
      w[j] = __expf(lrelu(als2[s[j]] + aldn));
      u[j] = *(const unsigned int*)(h2f8 + s[j] * CDIM + cp);
    }
#pragma unroll
    for (int j = 0; j < 4; j++) {
      f32x2 p0 = __builtin_amdgcn_cvt_pk_f32_fp8(u[j], false);
      f32x2 p1 = __builtin_amdgcn_cvt_pk_f32_fp8(u[j], true);
      a0 += w[j] * p0.x;
      a1 += w[j] * p0.y;
      a2 += w[j] * p1.x;
      a3 += w[j] * p1.y;
      zz += w[j];
    }
  }
  if (k + 8 <= end) {  // 8-slot half-chunk
    int s[2];
    float w[2];
    unsigned int u[2];
#pragma unroll
    for (int j = 0; j < 2; j++) s[j] = esrc[k + 4 * j + eg];
#pragma unroll
    for (int j = 0; j < 2; j++) {
      w[j] = __expf(lrelu(als2[s[j]] + aldn));
      u[j] = *(const unsigned int*)(h2f8 + s[j] * CDIM + cp);
    }
#pragma unroll
    for (int j = 0; j < 2; j++) {
      f32x2 p0 = __builtin_amdgcn_cvt_pk_f32_fp8(u[j], false);
      f32x2 p1 = __builtin_amdgcn_cvt_pk_f32_fp8(u[j], true);
      a0 += w[j] * p0.x;
      a1 += w[j] * p0.y;
      a2 += w[j] * p1.x;
      a3 += w[j] * p1.y;
      zz += w[j];
    }
    k += 8;
  }
  if (k < end) {  // 4-slot quarter-chunk
    int s0 = esrc[k + eg];
    float w0 = __expf(lrelu(als2[s0] + aldn));
    unsigned int u0 = *(const unsigned int*)(h2f8 + s0 * CDIM + cp);
    f32x2 p0 = __builtin_amdgcn_cvt_pk_f32_fp8(u0, false);
    f32x2 p1 = __builtin_amdgcn_cvt_pk_f32_fp8(u0, true);
    a0 += w0 * p0.x;
    a1 += w0 * p0.y;
    a2 += w0 * p1.x;
    a3 += w0 * p1.y;
    zz += w0;
  }
  // combine the four edge-groups (lanes sharing (lane&15) cover same channels)
  a0 += __shfl_xor(a0, 16, 64); a0 += __shfl_xor(a0, 32, 64);
  a1 += __shfl_xor(a1, 16, 64); a1 += __shfl_xor(a1, 32, 64);
  a2 += __shfl_xor(a2, 16, 64); a2 += __shfl_xor(a2, 32, 64);
  a3 += __shfl_xor(a3, 16, 64); a3 += __shfl_xor(a3, 32, 64);
  zz += __shfl_xor(zz, 16, 64); zz += __shfl_xor(zz, 32, 64);
  if (eg == 0) {
    float sw = __expf(lrelu(als2[node] + aldn));
    ushort4 vs = *(const ushort4*)(h2 + node * CDIM + cp);
    a0 += sw * bf2f(vs.x);
    a1 += sw * bf2f(vs.y);
    a2 += sw * bf2f(vs.z);
    a3 += sw * bf2f(vs.w);
    zz += sw;
    float inv = 1.f / zz;
    float4 bb = *(const float4*)(b2 + cp);
    svv[wave][cp + 0] = relu(a0 * inv + bb.x);
    svv[wave][cp + 1] = relu(a1 * inv + bb.y);
    svv[wave][cp + 2] = relu(a2 * inv + bb.z);
    svv[wave][cp + 3] = relu(a3 * inv + bb.w);
    if (lane == 0) sg[wave] = batch[node];
  }
  __syncthreads();
  int t = threadIdx.x;
  if (t < CDIM) {
    int g0 = sg[0], g1 = sg[1], g2 = sg[2], g3 = sg[3];
#pragma unroll
    for (int w = 0; w < 4; w++) {
      int gs[4] = {g0, g1, g2, g3};
      int gw = gs[w];
      bool first = true;
#pragma unroll
      for (int w2 = 0; w2 < 4; w2++)
        if (w2 < w && gs[w2] == gw) first = false;
      if (first) {
        float acc = svv[w][t];
#pragma unroll
        for (int w2 = 0; w2 < 4; w2++)
          if (w2 > w && gs[w2] == gw) acc += svv[w2][t];
        atomicAdd(&pooled[gw * CDIM + t], acc);
      }
    }
  }
}

// ---------------- pooled mean + classifier (f32 output); counts via binary search ----
__global__ void cls_kernel(const float* __restrict__ pooled, const int* __restrict__ batch,
                           const float* __restrict__ cW1, const float* __restrict__ cb1,
                           const float* __restrict__ cW2, const float* __restrict__ cb2,
                           float* __restrict__ out) {
  __shared__ float p[64];
  __shared__ float z[32];
  int g = blockIdx.x, t = threadIdx.x;
  int lo = 0, hi = NN;
  while (lo < hi) { int mid = (lo + hi) >> 1; if (batch[mid] < g) lo = mid + 1; else hi = mid; }
  int start = lo;
  lo = 0; hi = NN;
  while (lo < hi) { int mid = (lo + hi) >> 1; if (batch[mid] <= g) lo = mid + 1; else hi = mid; }
  int c = lo - start;
  float cnt = (float)(c > 0 ? c : 1);
  p[t] = pooled[g * CDIM + t] / cnt;
  __syncthreads();
  if (t < 32) {
    float a = cb1[t];
    for (int k = 0; k < 64; k++) a += p[k] * cW1[k * 32 + t];
    z[t] = relu(a);
  }
  __syncthreads();
  if (t < NCLS) {
    float a = cb2[t];
    for (int k = 0; k < 32; k++) a += z[k] * cW2[k * NCLS + t];
    out[g * NCLS + t] = a;
  }
}

extern "C" void kernel_launch(void* const* d_in, const int* in_sizes, int n_in,
                              void* d_out, int out_size, void* d_ws, size_t ws_size,
                              hipStream_t stream) {
  const float* x = (const float*)d_in[0];
  const int* edge_index = (const int*)d_in[1];
  const int* batch = (const int*)d_in[2];
  const float* W1 = (const float*)d_in[3];
  const float* a_src1 = (const float*)d_in[4];
  const float* a_dst1 = (const float*)d_in[5];
  const float* b1 = (const float*)d_in[6];
  const float* gamma = (const float*)d_in[7];
  const float* beta = (const float*)d_in[8];
  const float* W2 = (const float*)d_in[9];
  const float* a_src2 = (const float*)d_in[10];
  const float* a_dst2 = (const float*)d_in[11];
  const float* b2 = (const float*)d_in[12];
  const float* cW1 = (const float*)d_in[13];
  const float* cb1 = (const float*)d_in[14];
  const float* cW2 = (const float*)d_in[15];
  const float* cb2 = (const float*)d_in[16];

  // ---- workspace layout ----
  // zero region (contiguous, zeroed every call): deg8 | bnsum8 | bnsumsq8 | pooled
  int* deg8 = (int*)d_ws;
  float* bnsum8 = (float*)(deg8 + 8 * NN);
  float* bnsumsq8 = bnsum8 + 8 * HC;
  float* pooled = bnsumsq8 + 8 * HC;
  char* p = (char*)(pooled + NGRAPH * CDIM);
  auto align256 = [&](char*& q) {
    size_t a = (size_t)(q - (char*)d_ws);
    a = (a + 255) & ~(size_t)255;
    q = (char*)d_ws + a;
  };
  align256(p);
  int* degsum = (int*)p;          p += (size_t)NN * 4;       align256(p);
  int* offs = (int*)p;            p += (size_t)(NN + 1) * 4; align256(p);
  int* cursor8 = (int*)p;         p += (size_t)8 * NN * 4;   align256(p);
  int* esrc = (int*)p;            p += (size_t)(NE + 16 * NN) * 4; align256(p);
  int* bsum = (int*)p;            p += 256 * 4;              align256(p);
  unsigned short* h1 = (unsigned short*)p;   p += (size_t)NN * HC * 2;          align256(p);
  unsigned short* out1 = (unsigned short*)p; p += (size_t)NN * HC * 2;          align256(p);
  unsigned short* h2 = (unsigned short*)p;   p += (size_t)(NN + 1) * CDIM * 2;  align256(p);
  float* als1 = (float*)p;        p += (size_t)(NN + 1) * NHEAD * 4; align256(p);
  float* ald1 = (float*)p;        p += (size_t)NN * NHEAD * 4;       align256(p);
  float* als2v = (float*)p;       p += (size_t)(NN + 1) * 4;         align256(p);
  float* ald2v = (float*)p;       p += (size_t)NN * 4;               align256(p);
  unsigned char* h1f8 = (unsigned char*)p; p += (size_t)(NN + 1) * HC;  align256(p);
  unsigned char* h2f8 = (unsigned char*)p; p += (size_t)(NN + 1) * CDIM; align256(p);
  unsigned short* W1p = (unsigned short*)p; p += 32768 * 2;    align256(p);
  unsigned short* W2p = (unsigned short*)p; p += 16384 * 2;    align256(p);

  repack_kernel<<<(ZWORDS + 255) / 256, 256, 0, stream>>>(W1, W2, W1p, W2p, als1, als2v,
                                                          h1f8, h2, h2f8, (int*)d_ws);
  histgemm1_kernel<<<HB + (NT1 + 3) / 4, 256, 0, stream>>>(
      edge_index, deg8, x, W1p, a_src1, a_dst1, h1, h1f8, als1, ald1);
  scan_a<<<NB, 256, 0, stream>>>(deg8, bsum, degsum);
  scan_c<<<NB, 256, 0, stream>>>(degsum, deg8, bsum, offs, cursor8, esrc);
  scatter_kernel<<<2048, 256, 0, stream>>>(edge_index, cursor8, esrc);
  agg1_kernel<<<NN / 4, 256, 0, stream>>>(h1, h1f8, als1, ald1, offs, esrc, b1, out1,
                                          bnsum8, bnsumsq8);
  gemm2_kernel<<<(NT1 + 3) / 4, 256, 0, stream>>>(out1, W2p, bnsum8, bnsumsq8, gamma, beta,
                                                  a_src2, a_dst2, h2, h2f8, als2v, ald2v);
  agg2_kernel<<<NN / 4, 256, 0, stream>>>(h2, h2f8, als2v, ald2v, offs, esrc, b2,
                                          batch, pooled);
  cls_kernel<<<NGRAPH, 64, 0, stream>>>(pooled, batch, cW1, cb1, cW2, cb2, (float*)d_out);
}

// Round 13
// 256.115 us; speedup vs baseline: 1.2543x; 1.1176x over previous
//
#include <hip/hip_runtime.h>
#include <hip/hip_bf16.h>
#include <hip/hip_fp8.h>

#define NN 50000
#define NE 800000
#define DIN 128
#define HC 256
#define NHEAD 4
#define CDIM 64
#define NGRAPH 512
#define NCLS 10
#define NEG_SLOPE 0.2f
#define NT1 3125 // NN/16 M-tiles
#define CAP 64   // bucket capacity per node; Poisson(16) => P(deg>64) ~ 1e-19
// zero region words: bnsum8(8*HC) | bnsumsq8(8*HC) | pooled
#define ZWORDS (8 * HC + 8 * HC + NGRAPH * CDIM)

typedef __hip_bfloat16 bf16;
typedef __attribute__((ext_vector_type(8))) short short8;
typedef __attribute__((ext_vector_type(4))) float f32x4;
typedef __attribute__((ext_vector_type(2))) float f32x2;

__device__ __forceinline__ float bf2f(unsigned short u) {
  union { unsigned int i; float f; } x;
  x.i = ((unsigned int)u) << 16;
  return x.f;
}
__device__ __forceinline__ unsigned short f2bf(float f) {
  bf16 v = __float2bfloat16(f);
  union { bf16 b; unsigned short s; } x;
  x.b = v;
  return x.s;
}
// fp8 e4m3 (OCP) encode/decode via HIP type
__device__ __forceinline__ unsigned char f2f8(float f) {
  __hip_fp8_e4m3 q(f);
  return (unsigned char)q.__x;
}
__device__ __forceinline__ float lrelu(float x) { return x >= 0.f ? x : NEG_SLOPE * x; }
// NaN-propagating relu (fmaxf would silently clamp NaN to 0)
__device__ __forceinline__ float relu(float x) { return x < 0.f ? 0.f : x; }

// ---------------- FUSED init + repack ----------------
// Bucket-CSR init (replaces hist + scan_a + scan_c entirely): every node owns slots
// [64n, 64n+64) of esrcB; all slots pre-filled with sentinel NN (weight==0, zero
// payload) and cursor cur[n]=64n. Also zeroes the small accumulator region, repacks
// W1/W2 into MFMA B-frag bf16 order, and writes the sentinel rows.
__global__ void repack_kernel(const float* __restrict__ W1, const float* __restrict__ W2,
                              unsigned short* __restrict__ W1p, unsigned short* __restrict__ W2p,
                              float* __restrict__ als1, float* __restrict__ als2v,
                              unsigned char* __restrict__ h1f8, unsigned short* __restrict__ h2,
                              unsigned char* __restrict__ h2f8, int* __restrict__ zp,
                              int* __restrict__ esrcB, int* __restrict__ cur) {
  int i = blockIdx.x * 256 + threadIdx.x;
  if (i < CAP * NN) esrcB[i] = NN;
  if (i < NN) cur[i] = i * CAP;
  if (i < ZWORDS) zp[i] = 0;
  if (blockIdx.x == 0) {
    int t = threadIdx.x;
    if (t < NHEAD) als1[NN * NHEAD + t] = -1e30f;
    if (t == NHEAD) als2v[NN] = -1e30f;
    if (t < 64) ((unsigned int*)(h1f8 + (size_t)NN * HC))[t] = 0u;
    if (t < 32) ((unsigned int*)(h2 + (size_t)NN * CDIM))[t] = 0u;
    if (t < 16) ((unsigned int*)(h2f8 + (size_t)NN * CDIM))[t] = 0u;
  }
  if (i < 16 * 4 * 64 * 8) {  // W1: [128,256] -> ng(16) kk(4) lane(64) j(8)
    int j = i & 7, lane = (i >> 3) & 63, kk = (i >> 9) & 3, ng = i >> 11;
    int n = ng * 16 + (lane & 15);
    int k = kk * 32 + (lane >> 4) * 8 + j;
    W1p[i] = f2bf(W1[k * HC + n]);
  }
  int i2 = i - 16 * 4 * 64 * 8;
  if (i2 >= 0 && i2 < 4 * 8 * 64 * 8) {  // W2: [256,64] -> ng(4) kk(8) lane(64) j(8)
    int j = i2 & 7, lane = (i2 >> 3) & 63, kk = (i2 >> 9) & 7, ng = i2 >> 12;
    int n = ng * 16 + (lane & 15);
    int k = kk * 32 + (lane >> 4) * 8 + j;
    W2p[i2] = f2bf(W2[k * CDIM + n]);
  }
}

// ---------------- FUSED: XCD-affine bucket scatter (blocks 0..2047) + GEMM1 ---------
// r8-proven pairing (317.4 fused vs 321.2 separate). Scatter: block (chunk c, xcd x)
// writes only edges with dst/6250 == x, atomically bumping cur[d] (bucket base 64d,
// no scan needed). GEMM1 emits the fp8 shadow + fused als1/ald1.
__global__ __launch_bounds__(256) void scatgemm1_kernel(
    const int* __restrict__ ei, int* __restrict__ cur, int* __restrict__ esrcB,
    const float* __restrict__ x, const unsigned short* __restrict__ W1p,
    const float* __restrict__ a_src, const float* __restrict__ a_dst,
    unsigned short* __restrict__ h1, unsigned char* __restrict__ h1f8,
    float* __restrict__ als, float* __restrict__ ald) {
  __shared__ float sh_as[HC], sh_ad[HC];
  if (blockIdx.x < 2048) {
    int xcd = blockIdx.x & 7;
    int chunk = blockIdx.x >> 3;
    int lo = chunk * (NE / 256);
    int hi = lo + (NE / 256);
    for (int e = lo + threadIdx.x; e < hi; e += 256) {
      int d = ei[NE + e];
      if (d / (NN / 8) == xcd) {
        int s = ei[e];
        int p = atomicAdd(&cur[d], 1);
        esrcB[p] = s;
      }
    }
    return;
  }
  {
    int t = threadIdx.x;
    sh_as[t] = a_src[t];
    sh_ad[t] = a_dst[t];
  }
  __syncthreads();
  int wave = threadIdx.x >> 6, lane = threadIdx.x & 63;
  int tile = (blockIdx.x - 2048) * 4 + wave;
  if (tile >= NT1) return;
  int r0 = tile * 16, m = lane & 15, quad = lane >> 4;
  int row = r0 + m;
  short8 a[4];
#pragma unroll
  for (int kk = 0; kk < 4; kk++) {
    int kb = kk * 32 + quad * 8;
    float4 f0 = *(const float4*)(x + row * DIN + kb);
    float4 f1 = *(const float4*)(x + row * DIN + kb + 4);
    alignas(16) unsigned short tmp[8];
    tmp[0] = f2bf(f0.x); tmp[1] = f2bf(f0.y); tmp[2] = f2bf(f0.z); tmp[3] = f2bf(f0.w);
    tmp[4] = f2bf(f1.x); tmp[5] = f2bf(f1.y); tmp[6] = f2bf(f1.z); tmp[7] = f2bf(f1.w);
    a[kk] = *(const short8*)tmp;
  }
#pragma unroll
  for (int hg = 0; hg < 4; hg++) {
    float ps[4] = {0.f, 0.f, 0.f, 0.f};
    float pd[4] = {0.f, 0.f, 0.f, 0.f};
#pragma unroll
    for (int sub = 0; sub < 4; sub++) {
      int ng = hg * 4 + sub;
      f32x4 acc = {0.f, 0.f, 0.f, 0.f};
#pragma unroll
      for (int kk = 0; kk < 4; kk++) {
        short8 b = *(const short8*)(W1p + ((ng * 4 + kk) * 64 + lane) * 8);
        acc = __builtin_amdgcn_mfma_f32_16x16x32_bf16(a[kk], b, acc, 0, 0, 0);
      }
      int col = ng * 16 + m;
      float asv = sh_as[col], adv = sh_ad[col];
#pragma unroll
      for (int r = 0; r < 4; r++) {
        int rr = r0 + quad * 4 + r;
        h1[rr * HC + col] = f2bf(acc[r]);
        h1f8[rr * HC + col] = f2f8(acc[r]);
        ps[r] += acc[r] * asv;
        pd[r] += acc[r] * adv;
      }
    }
#pragma unroll
    for (int o = 1; o < 16; o <<= 1) {
#pragma unroll
      for (int r = 0; r < 4; r++) {
        ps[r] += __shfl_xor(ps[r], o, 64);
        pd[r] += __shfl_xor(pd[r], o, 64);
      }
    }
    if (m == 0) {
#pragma unroll
      for (int r = 0; r < 4; r++) {
        int rr = r0 + quad * 4 + r;
        als[rr * NHEAD + hg] = ps[r];
        ald[rr * NHEAD + hg] = pd[r];
      }
    }
  }
}

// ---------------- GAT layer1 aggregation + FUSED BN stats ----------------
// Bucket CSR: beg = 64*node, deg = cur[node]-beg, end = beg + round4(deg); pad
// slots hold sentinel NN (weight 0, zero payload). 2 edge-groups x 32 lanes x 8 fp8
// channels, 8 gathers in flight; 16-slot main chunks + 8-slot half + 4-slot quarter.
// BN stats LDS-combined + 8-sharded atomics (replaces the old bnstats kernel).
__global__ __launch_bounds__(256) void agg1_kernel(const unsigned short* __restrict__ h1,
                                                   const unsigned char* __restrict__ h1f8,
                                                   const float* __restrict__ als,
                                                   const float* __restrict__ ald,
                                                   const int* __restrict__ cur,
                                                   const int* __restrict__ esrcB,
                                                   const float* __restrict__ b1,
                                                   unsigned short* __restrict__ out1,
                                                   float* __restrict__ bnsum8,
                                                   float* __restrict__ bnsumsq8) {
  __shared__ float bns[4][HC];
  __shared__ float bnq[4][HC];
  int wave = threadIdx.x >> 6;
  int node = blockIdx.x * 4 + wave;
  int lane = threadIdx.x & 63;
  int eg = lane >> 5;
  int c0 = (lane & 31) * 8;
  int hh = c0 >> 6;
  int beg = node * CAP;
  int deg = cur[node] - beg;
  int end = beg + ((deg + 3) & ~3);
  float aldh = ald[node * NHEAD + hh];
  float a[8] = {0.f, 0.f, 0.f, 0.f, 0.f, 0.f, 0.f, 0.f};
  float zz = 0.f;
  int k = beg;
  for (; k + 16 <= end; k += 16) {
    int s[8];
    float w[8];
    uint2 u[8];
#pragma unroll
    for (int j = 0; j < 8; j++) s[j] = esrcB[k + 2 * j + eg];
#pragma unroll
    for (int j = 0; j < 8; j++) {
      w[j] = __expf(lrelu(als[s[j] * NHEAD + hh] + aldh));
      u[j] = *(const uint2*)(h1f8 + s[j] * HC + c0);
    }
#pragma unroll
    for (int j = 0; j < 8; j++) {
      f32x2 p0 = __builtin_amdgcn_cvt_pk_f32_fp8(u[j].x, false);
      f32x2 p1 = __builtin_amdgcn_cvt_pk_f32_fp8(u[j].x, true);
      f32x2 p2 = __builtin_amdgcn_cvt_pk_f32_fp8(u[j].y, false);
      f32x2 p3 = __builtin_amdgcn_cvt_pk_f32_fp8(u[j].y, true);
      a[0] += w[j] * p0.x; a[1] += w[j] * p0.y;
      a[2] += w[j] * p1.x; a[3] += w[j] * p1.y;
      a[4] += w[j] * p2.x; a[5] += w[j] * p2.y;
      a[6] += w[j] * p3.x; a[7] += w[j] * p3.y;
      zz += w[j];
    }
  }
  if (k + 8 <= end) {  // 8-slot half-chunk
    int s[4];
    float w[4];
    uint2 u[4];
#pragma unroll
    for (int j = 0; j < 4; j++) s[j] = esrcB[k + 2 * j + eg];
#pragma unroll
    for (int j = 0; j < 4; j++) {
      w[j] = __expf(lrelu(als[s[j] * NHEAD + hh] + aldh));
      u[j] = *(const uint2*)(h1f8 + s[j] * HC + c0);
    }
#pragma unroll
    for (int j = 0; j < 4; j++) {
      f32x2 p0 = __builtin_amdgcn_cvt_pk_f32_fp8(u[j].x, false);
      f32x2 p1 = __builtin_amdgcn_cvt_pk_f32_fp8(u[j].x, true);
      f32x2 p2 = __builtin_amdgcn_cvt_pk_f32_fp8(u[j].y, false);
      f32x2 p3 = __builtin_amdgcn_cvt_pk_f32_fp8(u[j].y, true);
      a[0] += w[j] * p0.x; a[1] += w[j] * p0.y;
      a[2] += w[j] * p1.x; a[3] += w[j] * p1.y;
      a[4] += w[j] * p2.x; a[5] += w[j] * p2.y;
      a[6] += w[j] * p3.x; a[7] += w[j] * p3.y;
      zz += w[j];
    }
    k += 8;
  }
  if (k < end) {  // 4-slot quarter-chunk
    int s[2];
    float w[2];
    uint2 u[2];
#pragma unroll
    for (int j = 0; j < 2; j++) s[j] = esrcB[k + 2 * j + eg];
#pragma unroll
    for (int j = 0; j < 2; j++) {
      w[j] = __expf(lrelu(als[s[j] * NHEAD + hh] + aldh));
      u[j] = *(const uint2*)(h1f8 + s[j] * HC + c0);
    }
#pragma unroll
    for (int j = 0; j < 2; j++) {
      f32x2 p0 = __builtin_amdgcn_cvt_pk_f32_fp8(u[j].x, false);
      f32x2 p1 = __builtin_amdgcn_cvt_pk_f32_fp8(u[j].x, true);
      f32x2 p2 = __builtin_amdgcn_cvt_pk_f32_fp8(u[j].y, false);
      f32x2 p3 = __builtin_amdgcn_cvt_pk_f32_fp8(u[j].y, true);
      a[0] += w[j] * p0.x; a[1] += w[j] * p0.y;
      a[2] += w[j] * p1.x; a[3] += w[j] * p1.y;
      a[4] += w[j] * p2.x; a[5] += w[j] * p2.y;
      a[6] += w[j] * p3.x; a[7] += w[j] * p3.y;
      zz += w[j];
    }
  }
  // combine the two edge-groups (lanes L and L^32 cover the same channels)
#pragma unroll
  for (int j = 0; j < 8; j++) a[j] += __shfl_xor(a[j], 32, 64);
  zz += __shfl_xor(zz, 32, 64);
  if (eg == 0) {
    // self-loop from bf16 original
    float sw = __expf(lrelu(als[node * NHEAD + hh] + aldh));
    ushort4 vs0 = *(const ushort4*)(h1 + node * HC + c0);
    ushort4 vs1 = *(const ushort4*)(h1 + node * HC + c0 + 4);
    a[0] += sw * bf2f(vs0.x); a[1] += sw * bf2f(vs0.y);
    a[2] += sw * bf2f(vs0.z); a[3] += sw * bf2f(vs0.w);
    a[4] += sw * bf2f(vs1.x); a[5] += sw * bf2f(vs1.y);
    a[6] += sw * bf2f(vs1.z); a[7] += sw * bf2f(vs1.w);
    zz += sw;
    float inv = 1.f / zz;
    float4 bb0 = *(const float4*)(b1 + c0);
    float4 bb1 = *(const float4*)(b1 + c0 + 4);
    float ov[8];
    ov[0] = a[0] * inv + bb0.x; ov[1] = a[1] * inv + bb0.y;
    ov[2] = a[2] * inv + bb0.z; ov[3] = a[3] * inv + bb0.w;
    ov[4] = a[4] * inv + bb1.x; ov[5] = a[5] * inv + bb1.y;
    ov[6] = a[6] * inv + bb1.z; ov[7] = a[7] * inv + bb1.w;
    ushort4 o0, o1;
    o0.x = f2bf(ov[0]); o0.y = f2bf(ov[1]);
    o0.z = f2bf(ov[2]); o0.w = f2bf(ov[3]);
    o1.x = f2bf(ov[4]); o1.y = f2bf(ov[5]);
    o1.z = f2bf(ov[6]); o1.w = f2bf(ov[7]);
    *(ushort4*)(out1 + node * HC + c0) = o0;
    *(ushort4*)(out1 + node * HC + c0 + 4) = o1;
#pragma unroll
    for (int q = 0; q < 8; q++) {
      bns[wave][c0 + q] = ov[q];
      bnq[wave][c0 + q] = ov[q] * ov[q];
    }
  }
  __syncthreads();
  {
    int t = threadIdx.x;  // one channel per thread
    float s = bns[0][t] + bns[1][t] + bns[2][t] + bns[3][t];
    float q2 = bnq[0][t] + bnq[1][t] + bnq[2][t] + bnq[3][t];
    int sh = (blockIdx.x & 7) * HC;
    atomicAdd(&bnsum8[sh + t], s);
    atomicAdd(&bnsumsq8[sh + t], q2);
  }
}

// ---------------- GEMM2 + fused als2/ald2 + fp8 shadow: h2 = relu(bn(out1)) @ W2 -----
__global__ __launch_bounds__(256) void gemm2_kernel(const unsigned short* __restrict__ out1,
                                                    const unsigned short* __restrict__ W2p,
                                                    const float* __restrict__ bnsum8,
                                                    const float* __restrict__ bnsumsq8,
                                                    const float* __restrict__ gamma,
                                                    const float* __restrict__ beta,
                                                    const float* __restrict__ a_src2,
                                                    const float* __restrict__ a_dst2,
                                                    unsigned short* __restrict__ h2,
                                                    unsigned char* __restrict__ h2f8,
                                                    float* __restrict__ als2,
                                                    float* __restrict__ ald2) {
  __shared__ float scale_s[HC], shift_s[HC];
  __shared__ float sh_as[CDIM], sh_ad[CDIM];
  {
    int t = threadIdx.x;
    float su = 0.f, sq = 0.f;
#pragma unroll
    for (int j = 0; j < 8; j++) {
      su += bnsum8[j * HC + t];
      sq += bnsumsq8[j * HC + t];
    }
    float mu = su / (float)NN;
    float var = sq / (float)NN - mu * mu;
    float sc = gamma[t] * rsqrtf(var + 1e-5f);
    scale_s[t] = sc;
    shift_s[t] = beta[t] - mu * sc;
    if (t < CDIM) {
      sh_as[t] = a_src2[t];
      sh_ad[t] = a_dst2[t];
    }
  }
  __syncthreads();
  int wave = threadIdx.x >> 6, lane = threadIdx.x & 63;
  int tile = blockIdx.x * 4 + wave;
  if (tile >= NT1) return;
  int r0 = tile * 16, m = lane & 15, quad = lane >> 4;
  int row = r0 + m;
  short8 a[8];
#pragma unroll
  for (int kk = 0; kk < 8; kk++) {
    int kb = kk * 32 + quad * 8;
    short8 raw = *(const short8*)(out1 + row * HC + kb);
    alignas(16) unsigned short tmp[8];
#pragma unroll
    for (int j = 0; j < 8; j++) {
      tmp[j] = f2bf(relu(bf2f((unsigned short)raw[j]) * scale_s[kb + j] + shift_s[kb + j]));
    }
    a[kk] = *(const short8*)tmp;
  }
  float ps[4] = {0.f, 0.f, 0.f, 0.f};
  float pd[4] = {0.f, 0.f, 0.f, 0.f};
#pragma unroll
  for (int ng = 0; ng < 4; ng++) {
    f32x4 acc = {0.f, 0.f, 0.f, 0.f};
#pragma unroll
    for (int kk = 0; kk < 8; kk++) {
      short8 b = *(const short8*)(W2p + ((ng * 8 + kk) * 64 + lane) * 8);
      acc = __builtin_amdgcn_mfma_f32_16x16x32_bf16(a[kk], b, acc, 0, 0, 0);
    }
    int col = ng * 16 + m;
    float asv = sh_as[col], adv = sh_ad[col];
#pragma unroll
    for (int r = 0; r < 4; r++) {
      int rr = r0 + quad * 4 + r;
      h2[rr * CDIM + col] = f2bf(acc[r]);
      h2f8[rr * CDIM + col] = f2f8(acc[r]);
      ps[r] += acc[r] * asv;
      pd[r] += acc[r] * adv;
    }
  }
#pragma unroll
  for (int o = 1; o < 16; o <<= 1) {
#pragma unroll
    for (int r = 0; r < 4; r++) {
      ps[r] += __shfl_xor(ps[r], o, 64);
      pd[r] += __shfl_xor(pd[r], o, 64);
    }
  }
  if (m == 0) {
#pragma unroll
    for (int r = 0; r < 4; r++) {
      int rr = r0 + quad * 4 + r;
      als2[rr] = ps[r];
      ald2[rr] = pd[r];
    }
  }
}

// ---------------- GAT layer2 agg + ReLU + pooling ----------------
// Bucket CSR (beg=64*node, deg from cur). 4 edge-groups x 16 lanes x 4 fp8 channels
// (uint gathers into the 3.2MB L2-resident h2f8; bf16 self-loop). Pooled atomics
// block-combined in LDS.
__global__ __launch_bounds__(256) void agg2_kernel(const unsigned short* __restrict__ h2,
                                                   const unsigned char* __restrict__ h2f8,
                                                   const float* __restrict__ als2,
                                                   const float* __restrict__ ald2,
                                                   const int* __restrict__ cur,
                                                   const int* __restrict__ esrcB,
                                                   const float* __restrict__ b2,
                                                   const int* __restrict__ batch,
                                                   float* __restrict__ pooled) {
  __shared__ float svv[4][CDIM];
  __shared__ int sg[4];
  int wave = threadIdx.x >> 6;
  int node = blockIdx.x * 4 + wave;
  int lane = threadIdx.x & 63;
  int eg = lane >> 4;          // 4 edge groups
  int cp = (lane & 15) * 4;    // 4 channels per lane
  int beg = node * CAP;
  int deg = cur[node] - beg;
  int end = beg + ((deg + 3) & ~3);
  float aldn = ald2[node];
  float a0 = 0.f, a1 = 0.f, a2 = 0.f, a3 = 0.f, zz = 0.f;
  int k = beg;
  for (; k + 16 <= end; k += 16) {
    int s[4];
    float w[4];
    unsigned int u[4];
#pragma unroll
    for (int j = 0; j < 4; j++) s[j] = esrcB[k + 4 * j + eg];
#pragma unroll
    for (int j = 0; j < 4; j++) {
      w[j] = __expf(lrelu(als2[s[j]] + aldn));
      u[j] = *(const unsigned int*)(h2f8 + s[j] * CDIM + cp);
    }
#pragma unroll
    for (int j = 0; j < 4; j++) {
      f32x2 p0 = __builtin_amdgcn_cvt_pk_f32_fp8(u[j], false);
      f32x2 p1 = __builtin_amdgcn_cvt_pk_f32_fp8(u[j], true);
      a0 += w[j] * p0.x;
      a1 += w[j] * p0.y;
      a2 += w[j] * p1.x;
      a3 += w[j] * p1.y;
      zz += w[j];
    }
  }
  if (k + 8 <= end) {  // 8-slot half-chunk
    int s[2];
    float w[2];
    unsigned int u[2];
#pragma unroll
    for (int j = 0; j < 2; j++) s[j] = esrcB[k + 4 * j + eg];
#pragma unroll
    for (int j = 0; j < 2; j++) {
      w[j] = __expf(lrelu(als2[s[j]] + aldn));
      u[j] = *(const unsigned int*)(h2f8 + s[j] * CDIM + cp);
    }
#pragma unroll
    for (int j = 0; j < 2; j++) {
      f32x2 p0 = __builtin_amdgcn_cvt_pk_f32_fp8(u[j], false);
      f32x2 p1 = __builtin_amdgcn_cvt_pk_f32_fp8(u[j], true);
      a0 += w[j] * p0.x;
      a1 += w[j] * p0.y;
      a2 += w[j] * p1.x;
      a3 += w[j] * p1.y;
      zz += w[j];
    }
    k += 8;
  }
  if (k < end) {  // 4-slot quarter-chunk
    int s0 = esrcB[k + eg];
    float w0 = __expf(lrelu(als2[s0] + aldn));
    unsigned int u0 = *(const unsigned int*)(h2f8 + s0 * CDIM + cp);
    f32x2 p0 = __builtin_amdgcn_cvt_pk_f32_fp8(u0, false);
    f32x2 p1 = __builtin_amdgcn_cvt_pk_f32_fp8(u0, true);
    a0 += w0 * p0.x;
    a1 += w0 * p0.y;
    a2 += w0 * p1.x;
    a3 += w0 * p1.y;
    zz += w0;
  }
  // combine the four edge-groups (lanes sharing (lane&15) cover same channels)
  a0 += __shfl_xor(a0, 16, 64); a0 += __shfl_xor(a0, 32, 64);
  a1 += __shfl_xor(a1, 16, 64); a1 += __shfl_xor(a1, 32, 64);
  a2 += __shfl_xor(a2, 16, 64); a2 += __shfl_xor(a2, 32, 64);
  a3 += __shfl_xor(a3, 16, 64); a3 += __shfl_xor(a3, 32, 64);
  zz += __shfl_xor(zz, 16, 64); zz += __shfl_xor(zz, 32, 64);
  if (eg == 0) {
    float sw = __expf(lrelu(als2[node] + aldn));
    ushort4 vs = *(const ushort4*)(h2 + node * CDIM + cp);
    a0 += sw * bf2f(vs.x);
    a1 += sw * bf2f(vs.y);
    a2 += sw * bf2f(vs.z);
    a3 += sw * bf2f(vs.w);
    zz += sw;
    float inv = 1.f / zz;
    float4 bb = *(const float4*)(b2 + cp);
    svv[wave][cp + 0] = relu(a0 * inv + bb.x);
    svv[wave][cp + 1] = relu(a1 * inv + bb.y);
    svv[wave][cp + 2] = relu(a2 * inv + bb.z);
    svv[wave][cp + 3] = relu(a3 * inv + bb.w);
    if (lane == 0) sg[wave] = batch[node];
  }
  __syncthreads();
  int t = threadIdx.x;
  if (t < CDIM) {
    int g0 = sg[0], g1 = sg[1], g2 = sg[2], g3 = sg[3];
#pragma unroll
    for (int w = 0; w < 4; w++) {
      int gs[4] = {g0, g1, g2, g3};
      int gw = gs[w];
      bool first = true;
#pragma unroll
      for (int w2 = 0; w2 < 4; w2++)
        if (w2 < w && gs[w2] == gw) first = false;
      if (first) {
        float acc = svv[w][t];
#pragma unroll
        for (int w2 = 0; w2 < 4; w2++)
          if (w2 > w && gs[w2] == gw) acc += svv[w2][t];
        atomicAdd(&pooled[gw * CDIM + t], acc);
      }
    }
  }
}

// ---------------- pooled mean + classifier (f32 output); counts via binary search ----
__global__ void cls_kernel(const float* __restrict__ pooled, const int* __restrict__ batch,
                           const float* __restrict__ cW1, const float* __restrict__ cb1,
                           const float* __restrict__ cW2, const float* __restrict__ cb2,
                           float* __restrict__ out) {
  __shared__ float p[64];
  __shared__ float z[32];
  int g = blockIdx.x, t = threadIdx.x;
  int lo = 0, hi = NN;
  while (lo < hi) { int mid = (lo + hi) >> 1; if (batch[mid] < g) lo = mid + 1; else hi = mid; }
  int start = lo;
  lo = 0; hi = NN;
  while (lo < hi) { int mid = (lo + hi) >> 1; if (batch[mid] <= g) lo = mid + 1; else hi = mid; }
  int c = lo - start;
  float cnt = (float)(c > 0 ? c : 1);
  p[t] = pooled[g * CDIM + t] / cnt;
  __syncthreads();
  if (t < 32) {
    float a = cb1[t];
    for (int k = 0; k < 64; k++) a += p[k] * cW1[k * 32 + t];
    z[t] = relu(a);
  }
  __syncthreads();
  if (t < NCLS) {
    float a = cb2[t];
    for (int k = 0; k < 32; k++) a += z[k] * cW2[k * NCLS + t];
    out[g * NCLS + t] = a;
  }
}

extern "C" void kernel_launch(void* const* d_in, const int* in_sizes, int n_in,
                              void* d_out, int out_size, void* d_ws, size_t ws_size,
                              hipStream_t stream) {
  const float* x = (const float*)d_in[0];
  const int* edge_index = (const int*)d_in[1];
  const int* batch = (const int*)d_in[2];
  const float* W1 = (const float*)d_in[3];
  const float* a_src1 = (const float*)d_in[4];
  const float* a_dst1 = (const float*)d_in[5];
  const float* b1 = (const float*)d_in[6];
  const float* gamma = (const float*)d_in[7];
  const float* beta = (const float*)d_in[8];
  const float* W2 = (const float*)d_in[9];
  const float* a_src2 = (const float*)d_in[10];
  const float* a_dst2 = (const float*)d_in[11];
  const float* b2 = (const float*)d_in[12];
  const float* cW1 = (const float*)d_in[13];
  const float* cb1 = (const float*)d_in[14];
  const float* cW2 = (const float*)d_in[15];
  const float* cb2 = (const float*)d_in[16];

  // ---- workspace layout ----
  // zero region (contiguous, zeroed in repack): bnsum8 | bnsumsq8 | pooled
  float* bnsum8 = (float*)d_ws;
  float* bnsumsq8 = bnsum8 + 8 * HC;
  float* pooled = bnsumsq8 + 8 * HC;
  char* p = (char*)(pooled + NGRAPH * CDIM);
  auto align256 = [&](char*& q) {
    size_t a = (size_t)(q - (char*)d_ws);
    a = (a + 255) & ~(size_t)255;
    q = (char*)d_ws + a;
  };
  align256(p);
  int* esrcB = (int*)p;           p += ((size_t)CAP * NN + 256) * 4; align256(p);
  int* cur = (int*)p;             p += (size_t)NN * 4;               align256(p);
  unsigned short* h1 = (unsigned short*)p;   p += (size_t)NN * HC * 2;          align256(p);
  unsigned short* out1 = (unsigned short*)p; p += (size_t)NN * HC * 2;          align256(p);
  unsigned short* h2 = (unsigned short*)p;   p += (size_t)(NN + 1) * CDIM * 2;  align256(p);
  float* als1 = (float*)p;        p += (size_t)(NN + 1) * NHEAD * 4; align256(p);
  float* ald1 = (float*)p;        p += (size_t)NN * NHEAD * 4;       align256(p);
  float* als2v = (float*)p;       p += (size_t)(NN + 1) * 4;         align256(p);
  float* ald2v = (float*)p;       p += (size_t)NN * 4;               align256(p);
  unsigned char* h1f8 = (unsigned char*)p; p += (size_t)(NN + 1) * HC;  align256(p);
  unsigned char* h2f8 = (unsigned char*)p; p += (size_t)(NN + 1) * CDIM; align256(p);
  unsigned short* W1p = (unsigned short*)p; p += 32768 * 2;    align256(p);
  unsigned short* W2p = (unsigned short*)p; p += 16384 * 2;    align256(p);

  const int RB = (CAP * NN + 255) / 256;  // 12500 blocks covers esrcB init (largest range)
  repack_kernel<<<RB, 256, 0, stream>>>(W1, W2, W1p, W2p, als1, als2v,
                                        h1f8, h2, h2f8, (int*)bnsum8, esrcB, cur);
  scatgemm1_kernel<<<2048 + (NT1 + 3) / 4, 256, 0, stream>>>(
      edge_index, cur, esrcB, x, W1p, a_src1, a_dst1, h1, h1f8, als1, ald1);
  agg1_kernel<<<NN / 4, 256, 0, stream>>>(h1, h1f8, als1, ald1, cur, esrcB, b1, out1,
                                          bnsum8, bnsumsq8);
  gemm2_kernel<<<(NT1 + 3) / 4, 256, 0, stream>>>(out1, W2p, bnsum8, bnsumsq8, gamma, beta,
                                                  a_src2, a_dst2, h2, h2f8, als2v, ald2v);
  agg2_kernel<<<NN / 4, 256, 0, stream>>>(h2, h2f8, als2v, ald2v, cur, esrcB, b2,
                                          batch, pooled);
  cls_kernel<<<NGRAPH, 64, 0, stream>>>(pooled, batch, cW1, cb1, cW2, cb2, (float*)d_out);
}

// Round 14
// 254.597 us; speedup vs baseline: 1.2618x; 1.0060x over previous
//
#include <hip/hip_runtime.h>
#include <hip/hip_bf16.h>
#include <hip/hip_fp8.h>

#define NN 50000
#define NE 800000
#define DIN 128
#define HC 256
#define NHEAD 4
#define CDIM 64
#define NGRAPH 512
#define NCLS 10
#define NEG_SLOPE 0.2f
#define NT1 3125 // NN/16 M-tiles
#define CAP 64   // bucket capacity per node; Poisson(16) => P(deg>64) ~ 1e-19
// zero region words: bnsum8(8*HC) | bnsumsq8(8*HC) | pooled
#define ZWORDS (8 * HC + 8 * HC + NGRAPH * CDIM)

typedef __hip_bfloat16 bf16;
typedef __attribute__((ext_vector_type(8))) short short8;
typedef __attribute__((ext_vector_type(4))) float f32x4;
typedef __attribute__((ext_vector_type(2))) float f32x2;

__device__ __forceinline__ float bf2f(unsigned short u) {
  union { unsigned int i; float f; } x;
  x.i = ((unsigned int)u) << 16;
  return x.f;
}
__device__ __forceinline__ unsigned short f2bf(float f) {
  bf16 v = __float2bfloat16(f);
  union { bf16 b; unsigned short s; } x;
  x.b = v;
  return x.s;
}
// fp8 e4m3 (OCP) encode/decode via HIP type
__device__ __forceinline__ unsigned char f2f8(float f) {
  __hip_fp8_e4m3 q(f);
  return (unsigned char)q.__x;
}
__device__ __forceinline__ float lrelu(float x) { return x >= 0.f ? x : NEG_SLOPE * x; }
// NaN-propagating relu (fmaxf would silently clamp NaN to 0)
__device__ __forceinline__ float relu(float x) { return x < 0.f ? 0.f : x; }

// ---------------- FUSED init + repack ----------------
// Bucket-CSR init (no hist/scan): every node owns slots [64n, 64n+64) of esrcB;
// all slots pre-filled with sentinel NN (weight==0, zero payload) and cursor
// cur[n]=64n. Also zeroes the small accumulator region, repacks W1/W2 into MFMA
// B-frag bf16 order, and writes the sentinel rows.
__global__ void repack_kernel(const float* __restrict__ W1, const float* __restrict__ W2,
                              unsigned short* __restrict__ W1p, unsigned short* __restrict__ W2p,
                              float* __restrict__ als1, float* __restrict__ als2v,
                              unsigned char* __restrict__ h1f8, unsigned short* __restrict__ h2,
                              unsigned char* __restrict__ h2f8, int* __restrict__ zp,
                              int* __restrict__ esrcB, int* __restrict__ cur) {
  int i = blockIdx.x * 256 + threadIdx.x;
  if (i < CAP * NN) esrcB[i] = NN;
  if (i < NN) cur[i] = i * CAP;
  if (i < ZWORDS) zp[i] = 0;
  if (blockIdx.x == 0) {
    int t = threadIdx.x;
    if (t < NHEAD) als1[NN * NHEAD + t] = -1e30f;
    if (t == NHEAD) als2v[NN] = -1e30f;
    if (t < 64) ((unsigned int*)(h1f8 + (size_t)NN * HC))[t] = 0u;
    if (t < 32) ((unsigned int*)(h2 + (size_t)NN * CDIM))[t] = 0u;
    if (t < 16) ((unsigned int*)(h2f8 + (size_t)NN * CDIM))[t] = 0u;
  }
  if (i < 16 * 4 * 64 * 8) {  // W1: [128,256] -> ng(16) kk(4) lane(64) j(8)
    int j = i & 7, lane = (i >> 3) & 63, kk = (i >> 9) & 3, ng = i >> 11;
    int n = ng * 16 + (lane & 15);
    int k = kk * 32 + (lane >> 4) * 8 + j;
    W1p[i] = f2bf(W1[k * HC + n]);
  }
  int i2 = i - 16 * 4 * 64 * 8;
  if (i2 >= 0 && i2 < 4 * 8 * 64 * 8) {  // W2: [256,64] -> ng(4) kk(8) lane(64) j(8)
    int j = i2 & 7, lane = (i2 >> 3) & 63, kk = (i2 >> 9) & 7, ng = i2 >> 12;
    int n = ng * 16 + (lane & 15);
    int k = kk * 32 + (lane >> 4) * 8 + j;
    W2p[i2] = f2bf(W2[k * CDIM + n]);
  }
}

// ---------------- FUSED: XCD-affine bucket scatter (blocks 0..2047) + GEMM1 ---------
// Scatter unrolled 4-deep: 4 independent dst loads + 4 independent atomic/store
// chains per round (the serial 12-iteration loop was the latency bottleneck —
// nothing overlapped). esrcB stores are nontemporal (12.8MB scattered, mostly
// L2-miss anyway; protects gemm1's streaming data). GEMM1 emits the fp8 shadow +
// fused als1/ald1.
__global__ __launch_bounds__(256) void scatgemm1_kernel(
    const int* __restrict__ ei, int* __restrict__ cur, int* __restrict__ esrcB,
    const float* __restrict__ x, const unsigned short* __restrict__ W1p,
    const float* __restrict__ a_src, const float* __restrict__ a_dst,
    unsigned short* __restrict__ h1, unsigned char* __restrict__ h1f8,
    float* __restrict__ als, float* __restrict__ ald) {
  __shared__ float sh_as[HC], sh_ad[HC];
  if (blockIdx.x < 2048) {
    int xcd = blockIdx.x & 7;
    int chunk = blockIdx.x >> 3;
    int lo = chunk * (NE / 256);  // 3125 edges per chunk
    int hi = lo + (NE / 256);
    int e = lo + threadIdx.x;
#pragma unroll 1
    for (int it = 0; it < 3; it++) {  // 3 rounds x 4x256 = 3072 edges
      int e0 = e, e1 = e + 256, e2 = e + 512, e3 = e + 768;
      int d0 = ei[NE + e0], d1 = ei[NE + e1], d2 = ei[NE + e2], d3 = ei[NE + e3];
      if (d0 / (NN / 8) == xcd) {
        int s = ei[e0];
        int p = atomicAdd(&cur[d0], 1);
        __builtin_nontemporal_store(s, &esrcB[p]);
      }
      if (d1 / (NN / 8) == xcd) {
        int s = ei[e1];
        int p = atomicAdd(&cur[d1], 1);
        __builtin_nontemporal_store(s, &esrcB[p]);
      }
      if (d2 / (NN / 8) == xcd) {
        int s = ei[e2];
        int p = atomicAdd(&cur[d2], 1);
        __builtin_nontemporal_store(s, &esrcB[p]);
      }
      if (d3 / (NN / 8) == xcd) {
        int s = ei[e3];
        int p = atomicAdd(&cur[d3], 1);
        __builtin_nontemporal_store(s, &esrcB[p]);
      }
      e += 1024;
    }
    if (e < hi) {  // tail: 53 edges
      int d = ei[NE + e];
      if (d / (NN / 8) == xcd) {
        int s = ei[e];
        int p = atomicAdd(&cur[d], 1);
        __builtin_nontemporal_store(s, &esrcB[p]);
      }
    }
    return;
  }
  {
    int t = threadIdx.x;
    sh_as[t] = a_src[t];
    sh_ad[t] = a_dst[t];
  }
  __syncthreads();
  int wave = threadIdx.x >> 6, lane = threadIdx.x & 63;
  int tile = (blockIdx.x - 2048) * 4 + wave;
  if (tile >= NT1) return;
  int r0 = tile * 16, m = lane & 15, quad = lane >> 4;
  int row = r0 + m;
  short8 a[4];
#pragma unroll
  for (int kk = 0; kk < 4; kk++) {
    int kb = kk * 32 + quad * 8;
    float4 f0 = *(const float4*)(x + row * DIN + kb);
    float4 f1 = *(const float4*)(x + row * DIN + kb + 4);
    alignas(16) unsigned short tmp[8];
    tmp[0] = f2bf(f0.x); tmp[1] = f2bf(f0.y); tmp[2] = f2bf(f0.z); tmp[3] = f2bf(f0.w);
    tmp[4] = f2bf(f1.x); tmp[5] = f2bf(f1.y); tmp[6] = f2bf(f1.z); tmp[7] = f2bf(f1.w);
    a[kk] = *(const short8*)tmp;
  }
#pragma unroll
  for (int hg = 0; hg < 4; hg++) {
    float ps[4] = {0.f, 0.f, 0.f, 0.f};
    float pd[4] = {0.f, 0.f, 0.f, 0.f};
#pragma unroll
    for (int sub = 0; sub < 4; sub++) {
      int ng = hg * 4 + sub;
      f32x4 acc = {0.f, 0.f, 0.f, 0.f};
#pragma unroll
      for (int kk = 0; kk < 4; kk++) {
        short8 b = *(const short8*)(W1p + ((ng * 4 + kk) * 64 + lane) * 8);
        acc = __builtin_amdgcn_mfma_f32_16x16x32_bf16(a[kk], b, acc, 0, 0, 0);
      }
      int col = ng * 16 + m;
      float asv = sh_as[col], adv = sh_ad[col];
#pragma unroll
      for (int r = 0; r < 4; r++) {
        int rr = r0 + quad * 4 + r;
        h1[rr * HC + col] = f2bf(acc[r]);
        h1f8[rr * HC + col] = f2f8(acc[r]);
        ps[r] += acc[r] * asv;
        pd[r] += acc[r] * adv;
      }
    }
#pragma unroll
    for (int o = 1; o < 16; o <<= 1) {
#pragma unroll
      for (int r = 0; r < 4; r++) {
        ps[r] += __shfl_xor(ps[r], o, 64);
        pd[r] += __shfl_xor(pd[r], o, 64);
      }
    }
    if (m == 0) {
#pragma unroll
      for (int r = 0; r < 4; r++) {
        int rr = r0 + quad * 4 + r;
        als[rr * NHEAD + hg] = ps[r];
        ald[rr * NHEAD + hg] = pd[r];
      }
    }
  }
}

// ---------------- GAT layer1 aggregation + FUSED BN stats ----------------
// Bucket CSR: beg = 64*node, deg = cur[node]-beg, end = beg + round4(deg); pad
// slots hold sentinel NN (weight 0, zero payload). 2 edge-groups x 32 lanes x 8 fp8
// channels, 8 gathers in flight; 16-slot main chunks + 8-slot half + 4-slot quarter.
// BN stats LDS-combined + 8-sharded atomics.
__global__ __launch_bounds__(256) void agg1_kernel(const unsigned short* __restrict__ h1,
                                                   const unsigned char* __restrict__ h1f8,
                                                   const float* __restrict__ als,
                                                   const float* __restrict__ ald,
                                                   const int* __restrict__ cur,
                                                   const int* __restrict__ esrcB,
                                                   const float* __restrict__ b1,
                                                   unsigned short* __restrict__ out1,
                                                   float* __restrict__ bnsum8,
                                                   float* __restrict__ bnsumsq8) {
  __shared__ float bns[4][HC];
  __shared__ float bnq[4][HC];
  int wave = threadIdx.x >> 6;
  int node = blockIdx.x * 4 + wave;
  int lane = threadIdx.x & 63;
  int eg = lane >> 5;
  int c0 = (lane & 31) * 8;
  int hh = c0 >> 6;
  int beg = node * CAP;
  int deg = cur[node] - beg;
  int end = beg + ((deg + 3) & ~3);
  float aldh = ald[node * NHEAD + hh];
  float a[8] = {0.f, 0.f, 0.f, 0.f, 0.f, 0.f, 0.f, 0.f};
  float zz = 0.f;
  int k = beg;
  for (; k + 16 <= end; k += 16) {
    int s[8];
    float w[8];
    uint2 u[8];
#pragma unroll
    for (int j = 0; j < 8; j++) s[j] = esrcB[k + 2 * j + eg];
#pragma unroll
    for (int j = 0; j < 8; j++) {
      w[j] = __expf(lrelu(als[s[j] * NHEAD + hh] + aldh));
      u[j] = *(const uint2*)(h1f8 + s[j] * HC + c0);
    }
#pragma unroll
    for (int j = 0; j < 8; j++) {
      f32x2 p0 = __builtin_amdgcn_cvt_pk_f32_fp8(u[j].x, false);
      f32x2 p1 = __builtin_amdgcn_cvt_pk_f32_fp8(u[j].x, true);
      f32x2 p2 = __builtin_amdgcn_cvt_pk_f32_fp8(u[j].y, false);
      f32x2 p3 = __builtin_amdgcn_cvt_pk_f32_fp8(u[j].y, true);
      a[0] += w[j] * p0.x; a[1] += w[j] * p0.y;
      a[2] += w[j] * p1.x; a[3] += w[j] * p1.y;
      a[4] += w[j] * p2.x; a[5] += w[j] * p2.y;
      a[6] += w[j] * p3.x; a[7] += w[j] * p3.y;
      zz += w[j];
    }
  }
  if (k + 8 <= end) {  // 8-slot half-chunk
    int s[4];
    float w[4];
    uint2 u[4];
#pragma unroll
    for (int j = 0; j < 4; j++) s[j] = esrcB[k + 2 * j + eg];
#pragma unroll
    for (int j = 0; j < 4; j++) {
      w[j] = __expf(lrelu(als[s[j] * NHEAD + hh] + aldh));
      u[j] = *(const uint2*)(h1f8 + s[j] * HC + c0);
    }
#pragma unroll
    for (int j = 0; j < 4; j++) {
      f32x2 p0 = __builtin_amdgcn_cvt_pk_f32_fp8(u[j].x, false);
      f32x2 p1 = __builtin_amdgcn_cvt_pk_f32_fp8(u[j].x, true);
      f32x2 p2 = __builtin_amdgcn_cvt_pk_f32_fp8(u[j].y, false);
      f32x2 p3 = __builtin_amdgcn_cvt_pk_f32_fp8(u[j].y, true);
      a[0] += w[j] * p0.x; a[1] += w[j] * p0.y;
      a[2] += w[j] * p1.x; a[3] += w[j] * p1.y;
      a[4] += w[j] * p2.x; a[5] += w[j] * p2.y;
      a[6] += w[j] * p3.x; a[7] += w[j] * p3.y;
      zz += w[j];
    }
    k += 8;
  }
  if (k < end) {  // 4-slot quarter-chunk
    int s[2];
    float w[2];
    uint2 u[2];
#pragma unroll
    for (int j = 0; j < 2; j++) s[j] = esrcB[k + 2 * j + eg];
#pragma unroll
    for (int j = 0; j < 2; j++) {
      w[j] = __expf(lrelu(als[s[j] * NHEAD + hh] + aldh));
      u[j] = *(const uint2*)(h1f8 + s[j] * HC + c0);
    }
#pragma unroll
    for (int j = 0; j < 2; j++) {
      f32x2 p0 = __builtin_amdgcn_cvt_pk_f32_fp8(u[j].x, false);
      f32x2 p1 = __builtin_amdgcn_cvt_pk_f32_fp8(u[j].x, true);
      f32x2 p2 = __builtin_amdgcn_cvt_pk_f32_fp8(u[j].y, false);
      f32x2 p3 = __builtin_amdgcn_cvt_pk_f32_fp8(u[j].y, true);
      a[0] += w[j] * p0.x; a[1] += w[j] * p0.y;
      a[2] += w[j] * p1.x; a[3] += w[j] * p1.y;
      a[4] += w[j] * p2.x; a[5] += w[j] * p2.y;
      a[6] += w[j] * p3.x; a[7] += w[j] * p3.y;
      zz += w[j];
    }
  }
  // combine the two edge-groups (lanes L and L^32 cover the same channels)
#pragma unroll
  for (int j = 0; j < 8; j++) a[j] += __shfl_xor(a[j], 32, 64);
  zz += __shfl_xor(zz, 32, 64);
  if (eg == 0) {
    // self-loop from bf16 original
    float sw = __expf(lrelu(als[node * NHEAD + hh] + aldh));
    ushort4 vs0 = *(const ushort4*)(h1 + node * HC + c0);
    ushort4 vs1 = *(const ushort4*)(h1 + node * HC + c0 + 4);
    a[0] += sw * bf2f(vs0.x); a[1] += sw * bf2f(vs0.y);
    a[2] += sw * bf2f(vs0.z); a[3] += sw * bf2f(vs0.w);
    a[4] += sw * bf2f(vs1.x); a[5] += sw * bf2f(vs1.y);
    a[6] += sw * bf2f(vs1.z); a[7] += sw * bf2f(vs1.w);
    zz += sw;
    float inv = 1.f / zz;
    float4 bb0 = *(const float4*)(b1 + c0);
    float4 bb1 = *(const float4*)(b1 + c0 + 4);
    float ov[8];
    ov[0] = a[0] * inv + bb0.x; ov[1] = a[1] * inv + bb0.y;
    ov[2] = a[2] * inv + bb0.z; ov[3] = a[3] * inv + bb0.w;
    ov[4] = a[4] * inv + bb1.x; ov[5] = a[5] * inv + bb1.y;
    ov[6] = a[6] * inv + bb1.z; ov[7] = a[7] * inv + bb1.w;
    ushort4 o0, o1;
    o0.x = f2bf(ov[0]); o0.y = f2bf(ov[1]);
    o0.z = f2bf(ov[2]); o0.w = f2bf(ov[3]);
    o1.x = f2bf(ov[4]); o1.y = f2bf(ov[5]);
    o1.z = f2bf(ov[6]); o1.w = f2bf(ov[7]);
    *(ushort4*)(out1 + node * HC + c0) = o0;
    *(ushort4*)(out1 + node * HC + c0 + 4) = o1;
#pragma unroll
    for (int q = 0; q < 8; q++) {
      bns[wave][c0 + q] = ov[q];
      bnq[wave][c0 + q] = ov[q] * ov[q];
    }
  }
  __syncthreads();
  {
    int t = threadIdx.x;  // one channel per thread
    float s = bns[0][t] + bns[1][t] + bns[2][t] + bns[3][t];
    float q2 = bnq[0][t] + bnq[1][t] + bnq[2][t] + bnq[3][t];
    int sh = (blockIdx.x & 7) * HC;
    atomicAdd(&bnsum8[sh + t], s);
    atomicAdd(&bnsumsq8[sh + t], q2);
  }
}

// ---------------- GEMM2 + fused als2/ald2 + fp8 shadow: h2 = relu(bn(out1)) @ W2 -----
__global__ __launch_bounds__(256) void gemm2_kernel(const unsigned short* __restrict__ out1,
                                                    const unsigned short* __restrict__ W2p,
                                                    const float* __restrict__ bnsum8,
                                                    const float* __restrict__ bnsumsq8,
                                                    const float* __restrict__ gamma,
                                                    const float* __restrict__ beta,
                                                    const float* __restrict__ a_src2,
                                                    const float* __restrict__ a_dst2,
                                                    unsigned short* __restrict__ h2,
                                                    unsigned char* __restrict__ h2f8,
                                                    float* __restrict__ als2,
                                                    float* __restrict__ ald2) {
  __shared__ float scale_s[HC], shift_s[HC];
  __shared__ float sh_as[CDIM], sh_ad[CDIM];
  {
    int t = threadIdx.x;
    float su = 0.f, sq = 0.f;
#pragma unroll
    for (int j = 0; j < 8; j++) {
      su += bnsum8[j * HC + t];
      sq += bnsumsq8[j * HC + t];
    }
    float mu = su / (float)NN;
    float var = sq / (float)NN - mu * mu;
    float sc = gamma[t] * rsqrtf(var + 1e-5f);
    scale_s[t] = sc;
    shift_s[t] = beta[t] - mu * sc;
    if (t < CDIM) {
      sh_as[t] = a_src2[t];
      sh_ad[t] = a_dst2[t];
    }
  }
  __syncthreads();
  int wave = threadIdx.x >> 6, lane = threadIdx.x & 63;
  int tile = blockIdx.x * 4 + wave;
  if (tile >= NT1) return;
  int r0 = tile * 16, m = lane & 15, quad = lane >> 4;
  int row = r0 + m;
  short8 a[8];
#pragma unroll
  for (int kk = 0; kk < 8; kk++) {
    int kb = kk * 32 + quad * 8;
    short8 raw = *(const short8*)(out1 + row * HC + kb);
    alignas(16) unsigned short tmp[8];
#pragma unroll
    for (int j = 0; j < 8; j++) {
      tmp[j] = f2bf(relu(bf2f((unsigned short)raw[j]) * scale_s[kb + j] + shift_s[kb + j]));
    }
    a[kk] = *(const short8*)tmp;
  }
  float ps[4] = {0.f, 0.f, 0.f, 0.f};
  float pd[4] = {0.f, 0.f, 0.f, 0.f};
#pragma unroll
  for (int ng = 0; ng < 4; ng++) {
    f32x4 acc = {0.f, 0.f, 0.f, 0.f};
#pragma unroll
    for (int kk = 0; kk < 8; kk++) {
      short8 b = *(const short8*)(W2p + ((ng * 8 + kk) * 64 + lane) * 8);
      acc = __builtin_amdgcn_mfma_f32_16x16x32_bf16(a[kk], b, acc, 0, 0, 0);
    }
    int col = ng * 16 + m;
    float asv = sh_as[col], adv = sh_ad[col];
#pragma unroll
    for (int r = 0; r < 4; r++) {
      int rr = r0 + quad * 4 + r;
      h2[rr * CDIM + col] = f2bf(acc[r]);
      h2f8[rr * CDIM + col] = f2f8(acc[r]);
      ps[r] += acc[r] * asv;
      pd[r] += acc[r] * adv;
    }
  }
#pragma unroll
  for (int o = 1; o < 16; o <<= 1) {
#pragma unroll
    for (int r = 0; r < 4; r++) {
      ps[r] += __shfl_xor(ps[r], o, 64);
      pd[r] += __shfl_xor(pd[r], o, 64);
    }
  }
  if (m == 0) {
#pragma unroll
    for (int r = 0; r < 4; r++) {
      int rr = r0 + quad * 4 + r;
      als2[rr] = ps[r];
      ald2[rr] = pd[r];
    }
  }
}

// ---------------- GAT layer2 agg + ReLU + pooling ----------------
// Bucket CSR (beg=64*node, deg from cur). 4 edge-groups x 16 lanes x 4 fp8 channels
// (uint gathers into the 3.2MB L2-resident h2f8; bf16 self-loop). Pooled atomics
// block-combined in LDS.
__global__ __launch_bounds__(256) void agg2_kernel(const unsigned short* __restrict__ h2,
                                                   const unsigned char* __restrict__ h2f8,
                                                   const float* __restrict__ als2,
                                                   const float* __restrict__ ald2,
                                                   const int* __restrict__ cur,
                                                   const int* __restrict__ esrcB,
                                                   const float* __restrict__ b2,
                                                   const int* __restrict__ batch,
                                                   float* __restrict__ pooled) {
  __shared__ float svv[4][CDIM];
  __shared__ int sg[4];
  int wave = threadIdx.x >> 6;
  int node = blockIdx.x * 4 + wave;
  int lane = threadIdx.x & 63;
  int eg = lane >> 4;          // 4 edge groups
  int cp = (lane & 15) * 4;    // 4 channels per lane
  int beg = node * CAP;
  int deg = cur[node] - beg;
  int end = beg + ((deg + 3) & ~3);
  float aldn = ald2[node];
  float a0 = 0.f, a1 = 0.f, a2 = 0.f, a3 = 0.f, zz = 0.f;
  int k = beg;
  for (; k + 16 <= end; k += 16) {
    int s[4];
    float w[4];
    unsigned int u[4];
#pragma unroll
    for (int j = 0; j < 4; j++) s[j] = esrcB[k + 4 * j + eg];
#pragma unroll
    for (int j = 0; j < 4; j++) {
      w[j] = __expf(lrelu(als2[s[j]] + aldn));
      u[j] = *(const unsigned int*)(h2f8 + s[j] * CDIM + cp);
    }
#pragma unroll
    for (int j = 0; j < 4; j++) {
      f32x2 p0 = __builtin_amdgcn_cvt_pk_f32_fp8(u[j], false);
      f32x2 p1 = __builtin_amdgcn_cvt_pk_f32_fp8(u[j], true);
      a0 += w[j] * p0.x;
      a1 += w[j] * p0.y;
      a2 += w[j] * p1.x;
      a3 += w[j] * p1.y;
      zz += w[j];
    }
  }
  if (k + 8 <= end) {  // 8-slot half-chunk
    int s[2];
    float w[2];
    unsigned int u[2];
#pragma unroll
    for (int j = 0; j < 2; j++) s[j] = esrcB[k + 4 * j + eg];
#pragma unroll
    for (int j = 0; j < 2; j++) {
      w[j] = __expf(lrelu(als2[s[j]] + aldn));
      u[j] = *(const unsigned int*)(h2f8 + s[j] * CDIM + cp);
    }
#pragma unroll
    for (int j = 0; j < 2; j++) {
      f32x2 p0 = __builtin_amdgcn_cvt_pk_f32_fp8(u[j], false);
      f32x2 p1 = __builtin_amdgcn_cvt_pk_f32_fp8(u[j], true);
      a0 += w[j] * p0.x;
      a1 += w[j] * p0.y;
      a2 += w[j] * p1.x;
      a3 += w[j] * p1.y;
      zz += w[j];
    }
    k += 8;
  }
  if (k < end) {  // 4-slot quarter-chunk
    int s0 = esrcB[k + eg];
    float w0 = __expf(lrelu(als2[s0] + aldn));
    unsigned int u0 = *(const unsigned int*)(h2f8 + s0 * CDIM + cp);
    f32x2 p0 = __builtin_amdgcn_cvt_pk_f32_fp8(u0, false);
    f32x2 p1 = __builtin_amdgcn_cvt_pk_f32_fp8(u0, true);
    a0 += w0 * p0.x;
    a1 += w0 * p0.y;
    a2 += w0 * p1.x;
    a3 += w0 * p1.y;
    zz += w0;
  }
  // combine the four edge-groups (lanes sharing (lane&15) cover same channels)
  a0 += __shfl_xor(a0, 16, 64); a0 += __shfl_xor(a0, 32, 64);
  a1 += __shfl_xor(a1, 16, 64); a1 += __shfl_xor(a1, 32, 64);
  a2 += __shfl_xor(a2, 16, 64); a2 += __shfl_xor(a2, 32, 64);
  a3 += __shfl_xor(a3, 16, 64); a3 += __shfl_xor(a3, 32, 64);
  zz += __shfl_xor(zz, 16, 64); zz += __shfl_xor(zz, 32, 64);
  if (eg == 0) {
    float sw = __expf(lrelu(als2[node] + aldn));
    ushort4 vs = *(const ushort4*)(h2 + node * CDIM + cp);
    a0 += sw * bf2f(vs.x);
    a1 += sw * bf2f(vs.y);
    a2 += sw * bf2f(vs.z);
    a3 += sw * bf2f(vs.w);
    zz += sw;
    float inv = 1.f / zz;
    float4 bb = *(const float4*)(b2 + cp);
    svv[wave][cp + 0] = relu(a0 * inv + bb.x);
    svv[wave][cp + 1] = relu(a1 * inv + bb.y);
    svv[wave][cp + 2] = relu(a2 * inv + bb.z);
    svv[wave][cp + 3] = relu(a3 * inv + bb.w);
    if (lane == 0) sg[wave] = batch[node];
  }
  __syncthreads();
  int t = threadIdx.x;
  if (t < CDIM) {
    int g0 = sg[0], g1 = sg[1], g2 = sg[2], g3 = sg[3];
#pragma unroll
    for (int w = 0; w < 4; w++) {
      int gs[4] = {g0, g1, g2, g3};
      int gw = gs[w];
      bool first = true;
#pragma unroll
      for (int w2 = 0; w2 < 4; w2++)
        if (w2 < w && gs[w2] == gw) first = false;
      if (first) {
        float acc = svv[w][t];
#pragma unroll
        for (int w2 = 0; w2 < 4; w2++)
          if (w2 > w && gs[w2] == gw) acc += svv[w2][t];
        atomicAdd(&pooled[gw * CDIM + t], acc);
      }
    }
  }
}

// ---------------- pooled mean + classifier (f32 output); counts via binary search ----
__global__ void cls_kernel(const float* __restrict__ pooled, const int* __restrict__ batch,
                           const float* __restrict__ cW1, const float* __restrict__ cb1,
                           const float* __restrict__ cW2, const float* __restrict__ cb2,
                           float* __restrict__ out) {
  __shared__ float p[64];
  __shared__ float z[32];
  int g = blockIdx.x, t = threadIdx.x;
  int lo = 0, hi = NN;
  while (lo < hi) { int mid = (lo + hi) >> 1; if (batch[mid] < g) lo = mid + 1; else hi = mid; }
  int start = lo;
  lo = 0; hi = NN;
  while (lo < hi) { int mid = (lo + hi) >> 1; if (batch[mid] <= g) lo = mid + 1; else hi = mid; }
  int c = lo - start;
  float cnt = (float)(c > 0 ? c : 1);
  p[t] = pooled[g * CDIM + t] / cnt;
  __syncthreads();
  if (t < 32) {
    float a = cb1[t];
    for (int k = 0; k < 64; k++) a += p[k] * cW1[k * 32 + t];
    z[t] = relu(a);
  }
  __syncthreads();
  if (t < NCLS) {
    float a = cb2[t];
    for (int k = 0; k < 32; k++) a += z[k] * cW2[k * NCLS + t];
    out[g * NCLS + t] = a;
  }
}

extern "C" void kernel_launch(void* const* d_in, const int* in_sizes, int n_in,
                              void* d_out, int out_size, void* d_ws, size_t ws_size,
                              hipStream_t stream) {
  const float* x = (const float*)d_in[0];
  const int* edge_index = (const int*)d_in[1];
  const int* batch = (const int*)d_in[2];
  const float* W1 = (const float*)d_in[3];
  const float* a_src1 = (const float*)d_in[4];
  const float* a_dst1 = (const float*)d_in[5];
  const float* b1 = (const float*)d_in[6];
  const float* gamma = (const float*)d_in[7];
  const float* beta = (const float*)d_in[8];
  const float* W2 = (const float*)d_in[9];
  const float* a_src2 = (const float*)d_in[10];
  const float* a_dst2 = (const float*)d_in[11];
  const float* b2 = (const float*)d_in[12];
  const float* cW1 = (const float*)d_in[13];
  const float* cb1 = (const float*)d_in[14];
  const float* cW2 = (const float*)d_in[15];
  const float* cb2 = (const float*)d_in[16];

  // ---- workspace layout ----
  // zero region (contiguous, zeroed in repack): bnsum8 | bnsumsq8 | pooled
  float* bnsum8 = (float*)d_ws;
  float* bnsumsq8 = bnsum8 + 8 * HC;
  float* pooled = bnsumsq8 + 8 * HC;
  char* p = (char*)(pooled + NGRAPH * CDIM);
  auto align256 = [&](char*& q) {
    size_t a = (size_t)(q - (char*)d_ws);
    a = (a + 255) & ~(size_t)255;
    q = (char*)d_ws + a;
  };
  align256(p);
  int* esrcB = (int*)p;           p += ((size_t)CAP * NN + 256) * 4; align256(p);
  int* cur = (int*)p;             p += (size_t)NN * 4;               align256(p);
  unsigned short* h1 = (unsigned short*)p;   p += (size_t)NN * HC * 2;          align256(p);
  unsigned short* out1 = (unsigned short*)p; p += (size_t)NN * HC * 2;          align256(p);
  unsigned short* h2 = (unsigned short*)p;   p += (size_t)(NN + 1) * CDIM * 2;  align256(p);
  float* als1 = (float*)p;        p += (size_t)(NN + 1) * NHEAD * 4; align256(p);
  float* ald1 = (float*)p;        p += (size_t)NN * NHEAD * 4;       align256(p);
  float* als2v = (float*)p;       p += (size_t)(NN + 1) * 4;         align256(p);
  float* ald2v = (float*)p;       p += (size_t)NN * 4;               align256(p);
  unsigned char* h1f8 = (unsigned char*)p; p += (size_t)(NN + 1) * HC;  align256(p);
  unsigned char* h2f8 = (unsigned char*)p; p += (size_t)(NN + 1) * CDIM; align256(p);
  unsigned short* W1p = (unsigned short*)p; p += 32768 * 2;    align256(p);
  unsigned short* W2p = (unsigned short*)p; p += 16384 * 2;    align256(p);

  const int RB = (CAP * NN + 255) / 256;  // 12500 blocks covers esrcB init (largest range)
  repack_kernel<<<RB, 256, 0, stream>>>(W1, W2, W1p, W2p, als1, als2v,
                                        h1f8, h2, h2f8, (int*)bnsum8, esrcB, cur);
  scatgemm1_kernel<<<2048 + (NT1 + 3) / 4, 256, 0, stream>>>(
      edge_index, cur, esrcB, x, W1p, a_src1, a_dst1, h1, h1f8, als1, ald1);
  agg1_kernel<<<NN / 4, 256, 0, stream>>>(h1, h1f8, als1, ald1, cur, esrcB, b1, out1,
                                          bnsum8, bnsumsq8);
  gemm2_kernel<<<(NT1 + 3) / 4, 256, 0, stream>>>(out1, W2p, bnsum8, bnsumsq8, gamma, beta,
                                                  a_src2, a_dst2, h2, h2f8, als2v, ald2v);
  agg2_kernel<<<NN / 4, 256, 0, stream>>>(h2, h2f8, als2v, ald2v, cur, esrcB, b2,
                                          batch, pooled);
  cls_kernel<<<NGRAPH, 64, 0, stream>>>(pooled, batch, cW1, cb1, cW2, cb2, (float*)d_out);
}